// Round 5
// baseline (1196.918 us; speedup 1.0000x reference)
//
#include <hip/hip_runtime.h>

// ---------------------------------------------------------------------------
// MultiDimensionalLSTM on MI355X.
// B=32, C=32, Y=X=128, win 4x4 -> grid 32x32 cells, F=512, R=128, gates 5R=640.
//
// R11: R9 falsified the congestion theory (cutting poll traffic 500x made it
// WORSE): per-stage cost is intrinsic MALL transport latency. Two levers:
//  (1) No vmcnt drain per step: R8's __syncthreads (which emits
//      s_waitcnt vmcnt(0)) replaced by raw s_barrier + lgkmcnt(0) only --
//      the barrier only guards the h2 LDS double buffer. Global stores drain
//      asynchronously; sentinel (data-as-flag) transport tolerates that.
//  (2) Intra-XCD hops through the shared per-XCD L2. bid->XCD is round-robin
//      (bid&7), so remap bid -> row-group g=bid&7: rows {4g..4g+3} x (s,hf)
//      = 16 blocks on one XCD. Sibling edge (every stage) + 24/31 up edges
//      become same-L2: producer publishes PLAIN stores (dirty line in shared
//      L2), consumer polls sc0-only loads (L1 bypass, L2 hit ~0.15us).
//      Cross-XCD edges can't see remote-dirty lines -> every value is DUAL
//      PUBLISHED: plain->primary + sc1->mirror (MALL, proven R8 path).
//      Consumer polls primary every retry, mirror every 8th retry, takes
//      whichever is non-sentinel. No XCD-id probing, no timeouts: if the
//      round-robin assumption is wrong it degrades to R8-mirror + lever 1.
// Everything else = R8 (verified): gate-major weight tiles in registers
// (4 waves = 1 wave/SIMD = 512-reg budget), own-left via LDS double buffer,
// in-register epilogue, merged sweep, sentinel 0xFF (NaN, unreachable).
// ---------------------------------------------------------------------------

typedef unsigned short u16;
typedef unsigned int u32;
typedef unsigned long long u64;
typedef __attribute__((ext_vector_type(8))) short short8;     // 8 bf16 (4 VGPRs)
typedef __attribute__((ext_vector_type(8))) unsigned short us8;
typedef __attribute__((ext_vector_type(4))) float floatx4;

__device__ inline u16 f2bf(float f) {               // RNE fp32 -> bf16
  unsigned u = __float_as_uint(f);
  u += 0x7fffu + ((u >> 16) & 1u);
  return (u16)(u >> 16);
}
__device__ inline float bf2f(u16 v) { return __uint_as_float(((unsigned)v) << 16); }

__device__ inline void async16(u16* lds, const u16* g) {
  __builtin_amdgcn_global_load_lds((const __attribute__((address_space(1))) void*)g,
                                   (__attribute__((address_space(3))) void*)lds, 16, 0, 0);
}

__device__ inline float sigf(float x) { return 1.f / (1.f + __expf(-x)); }
__device__ inline float tanh_fast(float x) { return 1.f - 2.f / (__expf(2.f * x) + 1.f); }

// sc1 (MALL) primitives for the mirror path.
__device__ inline u64 aload64(const u64* p) {
  return __hip_atomic_load(p, __ATOMIC_RELAXED, __HIP_MEMORY_SCOPE_AGENT);
}
__device__ inline void astore32(u32* p, u32 v) {
  __hip_atomic_store(p, v, __ATOMIC_RELAXED, __HIP_MEMORY_SCOPE_AGENT);
}
__device__ inline void astore64(u64* p, u64 v) {
  __hip_atomic_store(p, v, __ATOMIC_RELAXED, __HIP_MEMORY_SCOPE_AGENT);
}
// nonzero iff either u32 half of v is the sentinel 0xFFFFFFFF (SWAR).
__device__ inline u64 bad32(u64 v) {
  u64 nv = ~v;
  return (nv - 0x0000000100000001ull) & ~nv & 0x8000000080000000ull;
}
// split 4 u64 of packed (hi | lo<<16) words into hi-plane / lo-plane bf16x8
__device__ inline void unpack8(const u64 q[4], short8* H, short8* L) {
  union { u32 w[4]; short8 s; } uh, ul;
#pragma unroll
  for (int i = 0; i < 4; ++i) {
    u32 a = (u32)q[i], b = (u32)(q[i] >> 32);
    uh.w[i] = (a & 0xFFFFu) | (b << 16);
    ul.w[i] = (a >> 16) | (b & 0xFFFF0000u);
  }
  *H = uh.s; *L = ul.s;
}

// LDS-only barrier: no vmcnt drain (rule-18 fences around the raw barrier).
__device__ inline void barrier_lds() {
  __builtin_amdgcn_sched_barrier(0);
  __asm__ __volatile__("s_waitcnt lgkmcnt(0)" ::: "memory");
  __builtin_amdgcn_s_barrier();
  __builtin_amdgcn_sched_barrier(0);
}

// 4x sc0-only 8B loads (L1-bypass, served by the local XCD L2).
#define LD4_SC0(Q, VO, BASE)                                                 \
  asm volatile("global_load_dwordx2 %0, %4, %5 offset:0 sc0\n\t"             \
               "global_load_dwordx2 %1, %4, %5 offset:8 sc0\n\t"             \
               "global_load_dwordx2 %2, %4, %5 offset:16 sc0\n\t"            \
               "global_load_dwordx2 %3, %4, %5 offset:24 sc0"                \
               : "=v"(Q[0]), "=v"(Q[1]), "=v"(Q[2]), "=v"(Q[3])              \
               : "v"(VO), "s"(BASE))

// ---------------------------------------------------------------------------
// Prep 1: W [768][640] fp32 -> WxT_{h,l} [640 pcol][512 k] (pcol = r*5+g),
// WhT_{h,l} [640 col][256 k] in ORIGINAL column order, biasp [640 pcol].
// ---------------------------------------------------------------------------
__global__ __launch_bounds__(256) void k_wprep(const float* __restrict__ W,
                                               const float* __restrict__ bias,
                                               u16* __restrict__ WxT_h, u16* __restrict__ WxT_l,
                                               u16* __restrict__ WhT_h, u16* __restrict__ WhT_l,
                                               float* __restrict__ biasp) {
  int pcol = blockIdx.x;                       // 0..639
  int col  = (pcol % 5) * 128 + pcol / 5;      // original gate column
  for (int k = threadIdx.x; k < 768; k += 256) {
    float v = W[(size_t)k * 640 + col];
    u16 hi = f2bf(v);
    u16 lo = f2bf(v - bf2f(hi));
    if (k < 512) { WxT_h[(size_t)pcol * 512 + k] = hi; WxT_l[(size_t)pcol * 512 + k] = lo; }
    else { WhT_h[(size_t)col * 256 + (k - 512)] = hi; WhT_l[(size_t)col * 256 + (k - 512)] = lo; }
  }
  if (threadIdx.x == 0) biasp[pcol] = bias[col];
}

// ---------------------------------------------------------------------------
// Prep 2: gather x [B,C,Y,X] -> xs hi/lo [t][b][f].
// ---------------------------------------------------------------------------
__global__ __launch_bounds__(256) void k_xgather(const float* __restrict__ x,
                                                 u16* __restrict__ xs_h,
                                                 u16* __restrict__ xs_l) {
  int lane = threadIdx.x & 63;
  int pair = blockIdx.x * 4 + (threadIdx.x >> 6);  // t*32+b
  int t = pair >> 5, b = pair & 31;
  int y = t >> 3, x0 = (t & 7) * 16;
  int j = lane >> 2;
  int cbase = (lane & 3) * 8;
  const float* src = x + ((size_t)b * 32 * 128 + y) * 128 + x0 + j;
  us8 vh, vl;
#pragma unroll
  for (int u = 0; u < 8; ++u) {
    float f = src[(size_t)(cbase + u) * 16384];
    u16 hi = f2bf(f);
    vh[u] = hi;
    vl[u] = f2bf(f - bf2f(hi));
  }
  *(us8*)(xs_h + (size_t)pair * 512 + lane * 8) = vh;
  *(us8*)(xs_l + (size_t)pair * 512 + lane * 8) = vl;
}

// ---------------------------------------------------------------------------
// Input GEMM (split-bf16): M=32768, N=640, K=512. 128x128 tile, BK=32.
// Gp stored [t][pcol][32 b] (16B floatx4).
// ---------------------------------------------------------------------------
__global__ __launch_bounds__(256) void k_gemm_in(const u16* __restrict__ xs_h,
                                                 const u16* __restrict__ xs_l,
                                                 const u16* __restrict__ WxT_h,
                                                 const u16* __restrict__ WxT_l,
                                                 const float* __restrict__ biasp,
                                                 float* __restrict__ Gp) {
  __shared__ u16 Ah[128 * 32], Al[128 * 32];
  __shared__ u16 Bh[128 * 32], Bl[128 * 32];
  const int tid = threadIdx.x;
  const int wv = tid >> 6, lane = tid & 63;
  const int quad = lane >> 4, l16 = lane & 15;
  const int m0 = blockIdx.x * 128;
  const int n0 = blockIdx.y * 128;
  const int arow = lane >> 2;
  const int acol = (lane & 3) * 8;

  floatx4 acc[4][4] = {};

  for (int kt = 0; kt < 512; kt += 32) {
#pragma unroll
    for (int i = 0; i < 2; ++i) {
      int chunk = wv * 2 + i;
      int row = chunk * 16 + arow;
      size_t aoff = (size_t)(m0 + row) * 512 + kt + acol;
      size_t boff = (size_t)(n0 + row) * 512 + kt + acol;
      async16(&Ah[chunk * 512 + lane * 8], xs_h + aoff);
      async16(&Al[chunk * 512 + lane * 8], xs_l + aoff);
      async16(&Bh[chunk * 512 + lane * 8], WxT_h + boff);
      async16(&Bl[chunk * 512 + lane * 8], WxT_l + boff);
    }
    __syncthreads();
    short8 afh[4], afl[4], bfh[4], bfl[4];
#pragma unroll
    for (int mt = 0; mt < 4; ++mt) {
      int ro = ((wv & 1) * 64 + mt * 16 + l16) * 32 + quad * 8;
      afh[mt] = *(const short8*)&Ah[ro];
      afl[mt] = *(const short8*)&Al[ro];
    }
#pragma unroll
    for (int nt = 0; nt < 4; ++nt) {
      int ro = ((wv >> 1) * 64 + nt * 16 + l16) * 32 + quad * 8;
      bfh[nt] = *(const short8*)&Bh[ro];
      bfl[nt] = *(const short8*)&Bl[ro];
    }
#pragma unroll
    for (int mt = 0; mt < 4; ++mt)
#pragma unroll
      for (int nt = 0; nt < 4; ++nt) {
        floatx4 a = acc[mt][nt];
        a = __builtin_amdgcn_mfma_f32_16x16x32_bf16(afl[mt], bfh[nt], a, 0, 0, 0);
        a = __builtin_amdgcn_mfma_f32_16x16x32_bf16(afh[mt], bfl[nt], a, 0, 0, 0);
        a = __builtin_amdgcn_mfma_f32_16x16x32_bf16(afh[mt], bfh[nt], a, 0, 0, 0);
        acc[mt][nt] = a;
      }
    __syncthreads();
  }
#pragma unroll
  for (int nt = 0; nt < 4; ++nt) {
    int n = n0 + (wv >> 1) * 64 + nt * 16 + l16;
    float bv = biasp[n];
#pragma unroll
    for (int mt = 0; mt < 4; ++mt) {
      int mBase = m0 + (wv & 1) * 64 + mt * 16 + quad * 4;   // 4 consecutive m, same t
      int tt = mBase >> 5, bb = mBase & 31;
      floatx4 vv;
#pragma unroll
      for (int r = 0; r < 4; ++r) vv[r] = acc[mt][nt][r] + bv;
      *(floatx4*)&Gp[((size_t)tt * 640 + n) * 32 + bb] = vv;
    }
  }
}

// ---------------------------------------------------------------------------
// Persistent recurrence. Grid 128. XCD-grouped decode: g = bid&7 (HW XCD via
// round-robin), rows {4g..4g+3}; sub = bid>>3: h = g*4+(sub&3), s=(sub>>2)&1,
// hf = sub>>3. Sibling + 24/31 up edges intra-XCD (L2 path); 7 row-group
// crossings use the MALL mirror.
// ---------------------------------------------------------------------------
__global__ __launch_bounds__(256, 1) void k_rec(const u16* __restrict__ WhT_h,
                                                const u16* __restrict__ WhT_l,
                                                const float* __restrict__ Gp,
                                                u64* __restrict__ cbuf,   // primary c [t][128 r][32 b]
                                                u32* __restrict__ hb,     // primary h [t*32+b][128] hi|lo<<16
                                                u64* __restrict__ cbm,    // mirror c (MALL)
                                                u32* __restrict__ hbm,    // mirror h (MALL)
                                                float* __restrict__ out) {
  __shared__ u16 h2h[2][1024], h2l[2][1024];   // [buf][16 b][64 r], XOR-swizzled

  const int g   = blockIdx.x & 7;
  const int sub = blockIdx.x >> 3;
  const int h   = g * 4 + (sub & 3);
  const int s   = (sub >> 2) & 1;
  const int hf  = sub >> 3;
  const int sb = s * 16;
  const int tid = threadIdx.x;
  const int wv = tid >> 6, lane = tid & 63;
  const int quad = lane >> 4, l16 = lane & 15;
  const int r0 = hf * 64 + wv * 16;
  const int rg = r0 + l16;                     // this lane's r
  const int b0 = sb + quad * 4;                // this lane's batch base
  const u64* hbm64 = (const u64*)hbm;

  // ---- Wh fragments -> registers, once. ks: 0..3 up, 4..5 own-left, 6..7 sib.
  short8 Bw_h[5][8], Bw_l[5][8];
#pragma unroll
  for (int gg_ = 0; gg_ < 5; ++gg_) {
    const u16* ph = WhT_h + (size_t)(gg_ * 128 + rg) * 256 + quad * 8;
    const u16* pl = WhT_l + (size_t)(gg_ * 128 + rg) * 256 + quad * 8;
#pragma unroll
    for (int ks = 0; ks < 8; ++ks) {
      int kk;
      if (ks < 4)      kk = ks * 32;
      else if (ks < 6) kk = 128 + hf * 64 + (ks - 4) * 32;
      else             kk = 128 + (1 - hf) * 64 + (ks - 6) * 32;
      Bw_h[gg_][ks] = *(const short8*)(ph + kk);
      Bw_l[gg_][ks] = *(const short8*)(pl + kk);
    }
  }

  float cl[4] = {0.f, 0.f, 0.f, 0.f};          // c_left, this lane's 4 cells

  for (int w = 0; w < 32; ++w) {
    const int t = h * 32 + w;
    const bool upok = t > 32;                  // faithful off-by-one
    const bool leftok = w > 0;

    // gate biases from Gp (plain cached loads; in flight during the sweep)
    floatx4 gg[5];
    {
      const float* gpb = Gp + ((size_t)t * 640 + rg * 5) * 32 + b0;
#pragma unroll
      for (int g2 = 0; g2 < 5; ++g2) gg[g2] = *(const floatx4*)(gpb + g2 * 32);
    }

    u64 uq[4][4]; u64 sq[2][4]; u64 cq0 = 0, cq1 = 0;
    const int sk0 = (1 - hf) * 2;

    // ---- UP sweep: primary (sc0/L2) every retry, mirror (sc1/MALL) every 8th.
    if (upok) {
      const u32 vo_u = (u32)(((((t - 32) * 32 + sb + l16) * 128) + quad * 8) * 4);
      const u32 vo_c = (u32)(((((t - 32) * 128 + rg) * 32) + b0) * 4);
      int tries = 0;
      for (;;) {
        LD4_SC0(uq[0], vo_u, hb);
        LD4_SC0(uq[1], vo_u + 128, hb);
        LD4_SC0(uq[2], vo_u + 256, hb);
        LD4_SC0(uq[3], vo_u + 384, hb);
        asm volatile("global_load_dwordx2 %0, %2, %3 offset:0 sc0\n\t"
                     "global_load_dwordx2 %1, %2, %3 offset:8 sc0"
                     : "=v"(cq0), "=v"(cq1) : "v"(vo_c), "s"(cbuf));
        asm volatile("s_waitcnt vmcnt(0)"
                     : "+v"(uq[0][0]), "+v"(uq[0][1]), "+v"(uq[0][2]), "+v"(uq[0][3]),
                       "+v"(uq[1][0]), "+v"(uq[1][1]), "+v"(uq[1][2]), "+v"(uq[1][3]),
                       "+v"(uq[2][0]), "+v"(uq[2][1]), "+v"(uq[2][2]), "+v"(uq[2][3]),
                       "+v"(uq[3][0]), "+v"(uq[3][1]), "+v"(uq[3][2]), "+v"(uq[3][3]),
                       "+v"(cq0), "+v"(cq1) :: "memory");
        u64 badv = bad32(cq0) | bad32(cq1);
#pragma unroll
        for (int ks = 0; ks < 4; ++ks)
#pragma unroll
          for (int i = 0; i < 4; ++i) badv |= bad32(uq[ks][i]);
        if (!badv) break;
        if ((tries++ & 7) == 7) {              // mirror (MALL) probe
          const size_t ub = vo_u >> 3, cb = vo_c >> 3;
#pragma unroll
          for (int ks = 0; ks < 4; ++ks)
#pragma unroll
            for (int i = 0; i < 4; ++i) uq[ks][i] = aload64(hbm64 + ub + ks * 16 + i);
          cq0 = aload64(cbm + cb); cq1 = aload64(cbm + cb + 1);
          u64 b2 = bad32(cq0) | bad32(cq1);
#pragma unroll
          for (int ks = 0; ks < 4; ++ks)
#pragma unroll
            for (int i = 0; i < 4; ++i) b2 |= bad32(uq[ks][i]);
          if (!b2) break;
        }
        __builtin_amdgcn_s_sleep(1);
        __asm__ __volatile__("" ::: "memory");
      }
    }

    // ---- SIB sweep (sibling is ALWAYS same-XCD under the grouped mapping).
    if (leftok) {
      const u32 vo_s = (u32)(((((t - 1) * 32 + sb + l16) * 128) + quad * 8) * 4) + (u32)(sk0 * 128);
      int tries = 0;
      for (;;) {
        LD4_SC0(sq[0], vo_s, hb);
        LD4_SC0(sq[1], vo_s + 128, hb);
        asm volatile("s_waitcnt vmcnt(0)"
                     : "+v"(sq[0][0]), "+v"(sq[0][1]), "+v"(sq[0][2]), "+v"(sq[0][3]),
                       "+v"(sq[1][0]), "+v"(sq[1][1]), "+v"(sq[1][2]), "+v"(sq[1][3]) :: "memory");
        u64 badv = 0;
#pragma unroll
        for (int j = 0; j < 2; ++j)
#pragma unroll
          for (int i = 0; i < 4; ++i) badv |= bad32(sq[j][i]);
        if (!badv) break;
        if ((tries++ & 7) == 7) {              // mirror probe
          const size_t sbase = vo_s >> 3;
#pragma unroll
          for (int j = 0; j < 2; ++j)
#pragma unroll
            for (int i = 0; i < 4; ++i) sq[j][i] = aload64(hbm64 + sbase + j * 16 + i);
          u64 b2 = 0;
#pragma unroll
          for (int j = 0; j < 2; ++j)
#pragma unroll
            for (int i = 0; i < 4; ++i) b2 |= bad32(sq[j][i]);
          if (!b2) break;
        }
        __builtin_amdgcn_s_sleep(1);
        __asm__ __volatile__("" ::: "memory");
      }
    }

    floatx4 acc[5] = {};

    // ---- phase A: own-left MFMAs from LDS ----
    if (leftok) {
      const int bsel = (w - 1) & 1;
#pragma unroll
      for (int j = 0; j < 2; ++j) {
        int idx = (l16 * 64 + j * 32 + quad * 8) ^ ((l16 & 7) << 3);
        short8 ah = *(const short8*)&h2h[bsel][idx];
        short8 al = *(const short8*)&h2l[bsel][idx];
#pragma unroll
        for (int g2 = 0; g2 < 5; ++g2) {
          floatx4 a = acc[g2];
          a = __builtin_amdgcn_mfma_f32_16x16x32_bf16(al, Bw_h[g2][4 + j], a, 0, 0, 0);
          a = __builtin_amdgcn_mfma_f32_16x16x32_bf16(ah, Bw_l[g2][4 + j], a, 0, 0, 0);
          a = __builtin_amdgcn_mfma_f32_16x16x32_bf16(ah, Bw_h[g2][4 + j], a, 0, 0, 0);
          acc[g2] = a;
        }
      }
    }

    // ---- phase B: remote-dep MFMAs ----
    if (upok) {
#pragma unroll
      for (int ks = 0; ks < 4; ++ks) {
        short8 ah, al;
        unpack8(uq[ks], &ah, &al);
#pragma unroll
        for (int g2 = 0; g2 < 5; ++g2) {
          floatx4 a = acc[g2];
          a = __builtin_amdgcn_mfma_f32_16x16x32_bf16(al, Bw_h[g2][ks], a, 0, 0, 0);
          a = __builtin_amdgcn_mfma_f32_16x16x32_bf16(ah, Bw_l[g2][ks], a, 0, 0, 0);
          a = __builtin_amdgcn_mfma_f32_16x16x32_bf16(ah, Bw_h[g2][ks], a, 0, 0, 0);
          acc[g2] = a;
        }
      }
    }
    if (leftok) {
#pragma unroll
      for (int j = 0; j < 2; ++j) {
        short8 ah, al;
        unpack8(sq[j], &ah, &al);
#pragma unroll
        for (int g2 = 0; g2 < 5; ++g2) {
          floatx4 a = acc[g2];
          a = __builtin_amdgcn_mfma_f32_16x16x32_bf16(al, Bw_h[g2][6 + j], a, 0, 0, 0);
          a = __builtin_amdgcn_mfma_f32_16x16x32_bf16(ah, Bw_l[g2][6 + j], a, 0, 0, 0);
          a = __builtin_amdgcn_mfma_f32_16x16x32_bf16(ah, Bw_h[g2][6 + j], a, 0, 0, 0);
          acc[g2] = a;
        }
      }
    }

    // ---- in-register epilogue ----
    float c1v[4];
    c1v[0] = __uint_as_float((u32)cq0); c1v[1] = __uint_as_float((u32)(cq0 >> 32));
    c1v[2] = __uint_as_float((u32)cq1); c1v[3] = __uint_as_float((u32)(cq1 >> 32));
    float nh[4]; u32 hpack[4];
#pragma unroll
    for (int u = 0; u < 4; ++u) {
      float gi = acc[0][u] + gg[0][u];
      float gj = acc[1][u] + gg[1][u];
      float ga = acc[2][u] + gg[2][u];
      float gb = acc[3][u] + gg[3][u];
      float go = acc[4][u] + gg[4][u];
      float c1 = upok ? c1v[u] : 0.f;
      float c2 = leftok ? cl[u] : 0.f;
      float nc = c1 * sigf(ga) + c2 * sigf(gb) + sigf(gi) * tanh_fast(gj);
      float nhv = tanh_fast(nc) * sigf(go);
      cl[u] = nc;
      nh[u] = nhv;
      u16 hi = f2bf(nhv);
      u16 lo = f2bf(nhv - bf2f(hi));
      hpack[u] = (u32)hi | ((u32)lo << 16);
    }
    // dual publication: plain -> primary (local XCD L2), sc1 -> mirror (MALL)
    const size_t hbase = ((size_t)t * 32 + b0) * 128 + rg;
    const size_t cw = (((size_t)t * 128 + rg) * 32 + b0) >> 1;
    const u64 pk0 = (u64)__float_as_uint(cl[0]) | ((u64)__float_as_uint(cl[1]) << 32);
    const u64 pk1 = (u64)__float_as_uint(cl[2]) | ((u64)__float_as_uint(cl[3]) << 32);
#pragma unroll
    for (int u = 0; u < 4; ++u) hb[hbase + (size_t)u * 128] = hpack[u];
    cbuf[cw] = pk0; cbuf[cw + 1] = pk1;
#pragma unroll
    for (int u = 0; u < 4; ++u) astore32(hbm + hbase + (size_t)u * 128, hpack[u]);
    astore64(cbm + cw, pk0); astore64(cbm + cw + 1, pk1);
#pragma unroll
    for (int u = 0; u < 4; ++u)
      out[(((size_t)(b0 + u) * 32 + h) * 32 + w) * 128 + rg] = nh[u];
    // own-half h -> LDS for next step's phase A
    {
      const int bsel = w & 1;
#pragma unroll
      for (int u = 0; u < 4; ++u) {
        int bl = quad * 4 + u;
        int idx = (bl * 64 + wv * 16 + l16) ^ ((bl & 7) << 3);
        h2h[bsel][idx] = (u16)(hpack[u] & 0xFFFFu);
        h2l[bsel][idx] = (u16)(hpack[u] >> 16);
      }
    }
    barrier_lds();   // LDS-only: no vmcnt drain on the critical path
  }
}

// ---------------------------------------------------------------------------
extern "C" void kernel_launch(void* const* d_in, const int* in_sizes, int n_in,
                              void* d_out, int out_size, void* d_ws, size_t ws_size,
                              hipStream_t stream) {
  const float* x    = (const float*)d_in[0];   // [32,32,128,128]
  const float* W    = (const float*)d_in[1];   // [768,640]
  const float* bias = (const float*)d_in[2];   // [640]
  float* out = (float*)d_out;                  // [32,32,32,128]
  char* ws = (char*)d_ws;

  size_t off = 0;
  u16*   xs_h  = (u16*)(ws + off);  off += (size_t)32768 * 512 * 2;  // 33.6 MB
  u16*   xs_l  = (u16*)(ws + off);  off += (size_t)32768 * 512 * 2;  // 33.6 MB
  u16*   WxT_h = (u16*)(ws + off);  off += (size_t)640 * 512 * 2;
  u16*   WxT_l = (u16*)(ws + off);  off += (size_t)640 * 512 * 2;
  u16*   WhT_h = (u16*)(ws + off);  off += (size_t)640 * 256 * 2;
  u16*   WhT_l = (u16*)(ws + off);  off += (size_t)640 * 256 * 2;
  float* biasp = (float*)(ws + off); off += (size_t)640 * 4;
  float* Gp    = (float*)(ws + off); off += (size_t)1024 * 640 * 32 * 4; // 83.9 MB
  // primary state (sentinel 0xFF, contiguous memset)
  u64*   cbuf  = (u64*)(ws + off);  off += (size_t)1024 * 128 * 32 * 4;  // 16.8 MB
  u32*   hb    = (u32*)(ws + off);  off += (size_t)32768 * 128 * 4;      // 16.8 MB
  // mirror state aliases the xs region (xs dead after k_gemm_in):
  u64*   cbm   = (u64*)xs_h;                                              // 16.8 MB
  u32*   hbm   = (u32*)((char*)xs_h + (size_t)1024 * 128 * 32 * 4);       // 16.8 MB
  (void)ws_size;

  hipMemsetAsync(cbuf, 0xFF, (size_t)1024 * 128 * 32 * 4 + (size_t)32768 * 128 * 4, stream);
  k_wprep<<<dim3(640), dim3(256), 0, stream>>>(W, bias, WxT_h, WxT_l, WhT_h, WhT_l, biasp);
  k_xgather<<<dim3(8192), dim3(256), 0, stream>>>(x, xs_h, xs_l);
  k_gemm_in<<<dim3(256, 5), dim3(256), 0, stream>>>(xs_h, xs_l, WxT_h, WxT_l, biasp, Gp);
  // mirror sentinel-init AFTER gemm consumed xs (stream-ordered)
  hipMemsetAsync(cbm, 0xFF, (size_t)1024 * 128 * 32 * 4 + (size_t)32768 * 128 * 4, stream);
  k_rec<<<dim3(128), dim3(256), 0, stream>>>(WhT_h, WhT_l, Gp, cbuf, hb, cbm, hbm, out);
}

// Round 6
// 924.546 us; speedup vs baseline: 1.2946x; 1.2946x over previous
//
#include <hip/hip_runtime.h>

// ---------------------------------------------------------------------------
// MultiDimensionalLSTM on MI355X.
// B=32, C=32, Y=X=128, win 4x4 -> grid 32x32 cells, F=512, R=128, gates 5R=640.
// Input projection: one split-bf16 MFMA GEMM (unchanged, off critical path).
//
// R12: hop-count reduction. R7..R11 established: each cross-block MALL hop
// costs ~6us and R8's schedule had one on EVERY stage (sibling n-half).
// Restructure so a block owns the FULL 640 gate cols (no sibling):
//  - recurrence GEMM in fp16 single-plane (h & Wh fp16, fp32 acc): weights
//    640x256x2B = 320 VGPR/lane -> register-resident in a 4-wave block.
//    Error ~2e-4 RMS on gates, below the input-GEMM bf16 floor.
//  - 2-row bands: grid 32 = 16 row-pairs x 2 batch-halves. Block (s,H) owns
//    rows 2H,2H+1. Superstep u: compute B=(2H+1,u-1) then A=(2H,u).
//    A.left, B.up, B.left: intra-block (LDS double buffers, c in registers).
//    ONLY A.up crosses blocks -> 15 MALL hops total (was 63).
//  - B computed first: A's remote sweep (issued at superstep top) hides under
//    B's MFMAs; B's publication issues before A's poll (liveness).
// Transport: proven R8 data-as-flag (relaxed sc1 stores/loads at MALL,
// sentinel 0xFF.. = NaN patterns unreachable). No flags, no fences, no wbl2.
// Barrier: LDS-only (lgkmcnt) -- no per-step vmcnt drain (R9 lesson).
// ---------------------------------------------------------------------------

typedef unsigned short u16;
typedef unsigned int u32;
typedef unsigned long long u64;
typedef __attribute__((ext_vector_type(8))) short short8;     // 8 x 16-bit
typedef __attribute__((ext_vector_type(8))) unsigned short us8;
typedef __attribute__((ext_vector_type(4))) float floatx4;

union Frag2 { u64 q[2]; short8 s; };

__device__ inline u16 f2bf(float f) {               // RNE fp32 -> bf16
  unsigned u = __float_as_uint(f);
  u += 0x7fffu + ((u >> 16) & 1u);
  return (u16)(u >> 16);
}
__device__ inline float bf2f(u16 v) { return __uint_as_float(((unsigned)v) << 16); }
__device__ inline u16 f2h(float f) {                // RNE fp32 -> fp16
  _Float16 h = (_Float16)f;
  return *(u16*)&h;
}

__device__ inline void async16(u16* lds, const u16* g) {
  __builtin_amdgcn_global_load_lds((const __attribute__((address_space(1))) void*)g,
                                   (__attribute__((address_space(3))) void*)lds, 16, 0, 0);
}

__device__ inline float sigf(float x) { return 1.f / (1.f + __expf(-x)); }
__device__ inline float tanh_fast(float x) { return 1.f - 2.f / (__expf(2.f * x) + 1.f); }

// Relaxed agent-scope (sc1, MALL) primitives -- the proven R8 transport.
__device__ inline u64 aload64(const u64* p) {
  return __hip_atomic_load(p, __ATOMIC_RELAXED, __HIP_MEMORY_SCOPE_AGENT);
}
__device__ inline void astore16(u16* p, u16 v) {
  __hip_atomic_store(p, v, __ATOMIC_RELAXED, __HIP_MEMORY_SCOPE_AGENT);
}
__device__ inline void astore64(u64* p, u64 v) {
  __hip_atomic_store(p, v, __ATOMIC_RELAXED, __HIP_MEMORY_SCOPE_AGENT);
}
// SWAR sentinel checks (exact; R8-proven reasoning).
__device__ inline u64 bad32(u64 v) {      // any u32 half == 0xFFFFFFFF
  u64 nv = ~v;
  return (nv - 0x0000000100000001ull) & ~nv & 0x8000000080000000ull;
}
__device__ inline u64 bad16x4(u64 v) {    // any u16 lane == 0xFFFF
  u64 nv = ~v;
  return (nv - 0x0001000100010001ull) & ~nv & 0x8000800080008000ull;
}
__device__ inline u64 packf2(float a, float b) {
  return (u64)__float_as_uint(a) | ((u64)__float_as_uint(b) << 32);
}

// LDS-only barrier: no vmcnt drain (global stores drain async; sentinel-safe).
__device__ inline void barrier_lds() {
  __builtin_amdgcn_sched_barrier(0);
  __asm__ __volatile__("s_waitcnt lgkmcnt(0)" ::: "memory");
  __builtin_amdgcn_s_barrier();
  __builtin_amdgcn_sched_barrier(0);
}

// ---------------------------------------------------------------------------
// Prep 1: W [768][640] fp32 -> WxT_{h,l} [640 pcol][512 k] (pcol = r*5+g,
// split-bf16 for the input GEMM), Wh16 [640 col][256 k] fp16 (col = g*128+r,
// recurrence), biasp [640 pcol].
// ---------------------------------------------------------------------------
__global__ __launch_bounds__(256) void k_wprep(const float* __restrict__ W,
                                               const float* __restrict__ bias,
                                               u16* __restrict__ WxT_h, u16* __restrict__ WxT_l,
                                               u16* __restrict__ Wh16,
                                               float* __restrict__ biasp) {
  int pcol = blockIdx.x;                       // 0..639
  int col  = (pcol % 5) * 128 + pcol / 5;      // original gate column
  for (int k = threadIdx.x; k < 768; k += 256) {
    float v = W[(size_t)k * 640 + col];
    if (k < 512) {
      u16 hi = f2bf(v);
      WxT_h[(size_t)pcol * 512 + k] = hi;
      WxT_l[(size_t)pcol * 512 + k] = f2bf(v - bf2f(hi));
    } else {
      Wh16[(size_t)col * 256 + (k - 512)] = f2h(v);
    }
  }
  if (threadIdx.x == 0) biasp[pcol] = bias[col];
}

// ---------------------------------------------------------------------------
// Prep 2: gather x [B,C,Y,X] -> xs hi/lo [t][b][f].
// ---------------------------------------------------------------------------
__global__ __launch_bounds__(256) void k_xgather(const float* __restrict__ x,
                                                 u16* __restrict__ xs_h,
                                                 u16* __restrict__ xs_l) {
  int lane = threadIdx.x & 63;
  int pair = blockIdx.x * 4 + (threadIdx.x >> 6);  // t*32+b
  int t = pair >> 5, b = pair & 31;
  int y = t >> 3, x0 = (t & 7) * 16;
  int j = lane >> 2;
  int cbase = (lane & 3) * 8;
  const float* src = x + ((size_t)b * 32 * 128 + y) * 128 + x0 + j;
  us8 vh, vl;
#pragma unroll
  for (int u = 0; u < 8; ++u) {
    float f = src[(size_t)(cbase + u) * 16384];
    u16 hi = f2bf(f);
    vh[u] = hi;
    vl[u] = f2bf(f - bf2f(hi));
  }
  *(us8*)(xs_h + (size_t)pair * 512 + lane * 8) = vh;
  *(us8*)(xs_l + (size_t)pair * 512 + lane * 8) = vl;
}

// ---------------------------------------------------------------------------
// Input GEMM (split-bf16): M=32768, N=640, K=512. 128x128 tile, BK=32.
// Gp stored [t][pcol][32 b] (16B floatx4).
// ---------------------------------------------------------------------------
__global__ __launch_bounds__(256) void k_gemm_in(const u16* __restrict__ xs_h,
                                                 const u16* __restrict__ xs_l,
                                                 const u16* __restrict__ WxT_h,
                                                 const u16* __restrict__ WxT_l,
                                                 const float* __restrict__ biasp,
                                                 float* __restrict__ Gp) {
  __shared__ u16 Ah[128 * 32], Al[128 * 32];
  __shared__ u16 Bh[128 * 32], Bl[128 * 32];
  const int tid = threadIdx.x;
  const int wv = tid >> 6, lane = tid & 63;
  const int quad = lane >> 4, l16 = lane & 15;
  const int m0 = blockIdx.x * 128;
  const int n0 = blockIdx.y * 128;
  const int arow = lane >> 2;
  const int acol = (lane & 3) * 8;

  floatx4 acc[4][4] = {};

  for (int kt = 0; kt < 512; kt += 32) {
#pragma unroll
    for (int i = 0; i < 2; ++i) {
      int chunk = wv * 2 + i;
      int row = chunk * 16 + arow;
      size_t aoff = (size_t)(m0 + row) * 512 + kt + acol;
      size_t boff = (size_t)(n0 + row) * 512 + kt + acol;
      async16(&Ah[chunk * 512 + lane * 8], xs_h + aoff);
      async16(&Al[chunk * 512 + lane * 8], xs_l + aoff);
      async16(&Bh[chunk * 512 + lane * 8], WxT_h + boff);
      async16(&Bl[chunk * 512 + lane * 8], WxT_l + boff);
    }
    __syncthreads();
    short8 afh[4], afl[4], bfh[4], bfl[4];
#pragma unroll
    for (int mt = 0; mt < 4; ++mt) {
      int ro = ((wv & 1) * 64 + mt * 16 + l16) * 32 + quad * 8;
      afh[mt] = *(const short8*)&Ah[ro];
      afl[mt] = *(const short8*)&Al[ro];
    }
#pragma unroll
    for (int nt = 0; nt < 4; ++nt) {
      int ro = ((wv >> 1) * 64 + nt * 16 + l16) * 32 + quad * 8;
      bfh[nt] = *(const short8*)&Bh[ro];
      bfl[nt] = *(const short8*)&Bl[ro];
    }
#pragma unroll
    for (int mt = 0; mt < 4; ++mt)
#pragma unroll
      for (int nt = 0; nt < 4; ++nt) {
        floatx4 a = acc[mt][nt];
        a = __builtin_amdgcn_mfma_f32_16x16x32_bf16(afl[mt], bfh[nt], a, 0, 0, 0);
        a = __builtin_amdgcn_mfma_f32_16x16x32_bf16(afh[mt], bfl[nt], a, 0, 0, 0);
        a = __builtin_amdgcn_mfma_f32_16x16x32_bf16(afh[mt], bfh[nt], a, 0, 0, 0);
        acc[mt][nt] = a;
      }
    __syncthreads();
  }
#pragma unroll
  for (int nt = 0; nt < 4; ++nt) {
    int n = n0 + (wv >> 1) * 64 + nt * 16 + l16;
    float bv = biasp[n];
#pragma unroll
    for (int mt = 0; mt < 4; ++mt) {
      int mBase = m0 + (wv & 1) * 64 + mt * 16 + quad * 4;   // 4 consecutive m, same t
      int tt = mBase >> 5, bb = mBase & 31;
      floatx4 vv;
#pragma unroll
      for (int r = 0; r < 4; ++r) vv[r] = acc[mt][nt][r] + bv;
      *(floatx4*)&Gp[((size_t)tt * 640 + n) * 32 + bb] = vv;
    }
  }
}

// ---------------------------------------------------------------------------
// Persistent recurrence, 2-row bands, full-N blocks, fp16 GEMM.
// Grid 32: bid = H*2 + s (lower H first). Block 256 thr = 4 waves = 1/SIMD.
// Block (s,H): rows 2H,2H+1; batches sb..sb+15; all 640 gate cols.
// Wave wv: r in {wv*16+l16, 64+wv*16+l16}; lane cells: 2 rb x 4 batches.
// hb:  fp16 h state, [t*32+b][128 r]  (sentinel 0xFFFF = fp16 NaN).
// cbuf: fp32 c state, [t][128 r][32 b] (sentinel 0xFFFFFFFF = NaN).
// ---------------------------------------------------------------------------
__global__ __launch_bounds__(256, 1) void k_rec(const u16* __restrict__ Wh16,
                                                const float* __restrict__ Gp,
                                                u64* __restrict__ cbuf,
                                                u16* __restrict__ hb,
                                                float* __restrict__ out) {
  __shared__ u16 hA[2][16 * 136], hB[2][16 * 136];   // [buf][local b][r], pad 136

  const int s = blockIdx.x & 1, H = blockIdx.x >> 1;
  const int sb = s * 16;
  const int tid = threadIdx.x;
  const int wv = tid >> 6, lane = tid & 63;
  const int quad = lane >> 4, l16 = lane & 15;
  const int rgA = wv * 16 + l16;            // rb=0 r
  const int rgB = 64 + wv * 16 + l16;       // rb=1 r
  const int b0 = sb + quad * 4;             // global batch base
  const int bl0 = quad * 4;                 // local batch base
  const int row0 = 2 * H, row1 = 2 * H + 1;
  const u64* hb64 = (const u64*)hb;

  // ---- Wh fp16 fragments -> registers, once. nt = rb*5+g; ks = k/32.
  short8 Bw[10][8];
#pragma unroll
  for (int rb = 0; rb < 2; ++rb)
#pragma unroll
    for (int g = 0; g < 5; ++g) {
      const u16* p = Wh16 + (size_t)(g * 128 + rb * 64 + wv * 16 + l16) * 256 + quad * 8;
#pragma unroll
      for (int ks = 0; ks < 8; ++ks)
        Bw[rb * 5 + g][ks] = *(const short8*)(p + ks * 32);
    }

  float cA[2][4] = {}, cB[2][4] = {};       // c state for rows 2H / 2H+1

  for (int u = 0; u <= 32; ++u) {
    const bool hasA = (u < 32), hasB = (u >= 1);
    const int wA = u, wB = u - 1;
    const int tA = row0 * 32 + wA, tB = row1 * 32 + wB;
    const bool upA = (H >= 1);              // row0: t=64H+u>32 iff H>=1 (H=0 never)
    const bool leftA = (u > 0);
    const bool upB = (H >= 1) || (u >= 2);  // faithful off-by-one at (1,0)
    const bool leftB = (u >= 2);
    const int pA = (u + 1) & 1;             // previous LDS buffer
    const int cur = u & 1;

    // ---- issue A's remote sweep (lands during B's compute) ----
    u64 uq[4][2]; u64 cq[4];
    size_t ub = 0, c0 = 0, c1i = 0;
    const bool needR = upA && hasA;
    if (needR) {
      ub  = (((size_t)(tA - 32) * 32 + sb + l16) * 128 + quad * 8) >> 2;   // u64 idx
      c0  = (((size_t)(tA - 32) * 128 + rgA) * 32 + b0) >> 1;
      c1i = (((size_t)(tA - 32) * 128 + rgB) * 32 + b0) >> 1;
#pragma unroll
      for (int ks = 0; ks < 4; ++ks) {
        uq[ks][0] = aload64(hb64 + ub + ks * 8);
        uq[ks][1] = aload64(hb64 + ub + ks * 8 + 1);
      }
      cq[0] = aload64(cbuf + c0);  cq[1] = aload64(cbuf + c0 + 1);
      cq[2] = aload64(cbuf + c1i); cq[3] = aload64(cbuf + c1i + 1);
    }

    // ---- gate-bias prefetch (plain cached loads; Gp is read-once) ----
    floatx4 ggB[10], ggA[10];
    if (hasB) {
#pragma unroll
      for (int rb = 0; rb < 2; ++rb)
#pragma unroll
        for (int g = 0; g < 5; ++g)
          ggB[rb * 5 + g] = *(const floatx4*)(Gp + ((size_t)tB * 640 + (rb ? rgB : rgA) * 5 + g) * 32 + b0);
    }
    if (hasA) {
#pragma unroll
      for (int rb = 0; rb < 2; ++rb)
#pragma unroll
        for (int g = 0; g < 5; ++g)
          ggA[rb * 5 + g] = *(const floatx4*)(Gp + ((size_t)tA * 640 + (rb ? rgB : rgA) * 5 + g) * 32 + b0);
    }

    // ================= cell B = (row1, wB): all-local =================
    if (hasB) {
      floatx4 acc[10] = {};
      if (upB) {                            // up = A of previous superstep (LDS)
#pragma unroll
        for (int ks = 0; ks < 4; ++ks) {
          short8 a = *(const short8*)&hA[pA][l16 * 136 + ks * 32 + quad * 8];
#pragma unroll
          for (int nt = 0; nt < 10; ++nt)
            acc[nt] = __builtin_amdgcn_mfma_f32_16x16x32_f16(a, Bw[nt][ks], acc[nt], 0, 0, 0);
        }
      }
      if (leftB) {                          // left = B of previous superstep (LDS)
#pragma unroll
        for (int ks = 0; ks < 4; ++ks) {
          short8 a = *(const short8*)&hB[pA][l16 * 136 + ks * 32 + quad * 8];
#pragma unroll
          for (int nt = 0; nt < 10; ++nt)
            acc[nt] = __builtin_amdgcn_mfma_f32_16x16x32_f16(a, Bw[nt][4 + ks], acc[nt], 0, 0, 0);
        }
      }
      // epilogue + publication (B feeds block H+1 -> MALL sentinel stores)
#pragma unroll
      for (int rb = 0; rb < 2; ++rb) {
        const int rg = rb ? rgB : rgA;
#pragma unroll
        for (int uu = 0; uu < 4; ++uu) {
          float gi = acc[rb * 5 + 0][uu] + ggB[rb * 5 + 0][uu];
          float gj = acc[rb * 5 + 1][uu] + ggB[rb * 5 + 1][uu];
          float ga = acc[rb * 5 + 2][uu] + ggB[rb * 5 + 2][uu];
          float gb = acc[rb * 5 + 3][uu] + ggB[rb * 5 + 3][uu];
          float go = acc[rb * 5 + 4][uu] + ggB[rb * 5 + 4][uu];
          float c1 = upB ? cA[rb][uu] : 0.f;       // register hand-off from row0
          float c2 = leftB ? cB[rb][uu] : 0.f;
          float nc = c1 * sigf(ga) + c2 * sigf(gb) + sigf(gi) * tanh_fast(gj);
          float nh = tanh_fast(nc) * sigf(go);
          cB[rb][uu] = nc;
          u16 hv = f2h(nh);
          astore16(hb + ((size_t)tB * 32 + b0 + uu) * 128 + rg, hv);
          out[(((size_t)(b0 + uu) * 32 + row1) * 32 + wB) * 128 + rg] = nh;
          hB[cur][(bl0 + uu) * 136 + rg] = hv;
        }
        size_t cwi = (((size_t)tB * 128 + rg) * 32 + b0) >> 1;
        astore64(cbuf + cwi,     packf2(cB[rb][0], cB[rb][1]));
        astore64(cbuf + cwi + 1, packf2(cB[rb][2], cB[rb][3]));
      }
    }

    // ================= cell A = (row0, wA): remote up =================
    if (hasA) {
      if (needR) {                          // sentinel poll (merged sweep)
        for (;;) {
          u64 bad = 0;
#pragma unroll
          for (int ks = 0; ks < 4; ++ks)
            bad |= bad16x4(uq[ks][0]) | bad16x4(uq[ks][1]);
          bad |= bad32(cq[0]) | bad32(cq[1]) | bad32(cq[2]) | bad32(cq[3]);
          if (!bad) break;
          __builtin_amdgcn_s_sleep(1);
          __asm__ __volatile__("" ::: "memory");
#pragma unroll
          for (int ks = 0; ks < 4; ++ks) {
            uq[ks][0] = aload64(hb64 + ub + ks * 8);
            uq[ks][1] = aload64(hb64 + ub + ks * 8 + 1);
          }
          cq[0] = aload64(cbuf + c0);  cq[1] = aload64(cbuf + c0 + 1);
          cq[2] = aload64(cbuf + c1i); cq[3] = aload64(cbuf + c1i + 1);
        }
      }
      floatx4 acc[10] = {};
      if (upA) {                            // up fragments straight from sweep regs
#pragma unroll
        for (int ks = 0; ks < 4; ++ks) {
          Frag2 f; f.q[0] = uq[ks][0]; f.q[1] = uq[ks][1];
#pragma unroll
          for (int nt = 0; nt < 10; ++nt)
            acc[nt] = __builtin_amdgcn_mfma_f32_16x16x32_f16(f.s, Bw[nt][ks], acc[nt], 0, 0, 0);
        }
      }
      if (leftA) {                          // left = own A of previous superstep
#pragma unroll
        for (int ks = 0; ks < 4; ++ks) {
          short8 a = *(const short8*)&hA[pA][l16 * 136 + ks * 32 + quad * 8];
#pragma unroll
          for (int nt = 0; nt < 10; ++nt)
            acc[nt] = __builtin_amdgcn_mfma_f32_16x16x32_f16(a, Bw[nt][4 + ks], acc[nt], 0, 0, 0);
        }
      }
      // epilogue (A is intra-consumed: out + LDS only, no MALL publication)
#pragma unroll
      for (int rb = 0; rb < 2; ++rb) {
        const int rg = rb ? rgB : rgA;
#pragma unroll
        for (int uu = 0; uu < 4; ++uu) {
          float c1 = 0.f;
          if (upA) {
            u64 q = cq[rb * 2 + (uu >> 1)];
            c1 = __uint_as_float((u32)(q >> (32 * (uu & 1))));
          }
          float gi = acc[rb * 5 + 0][uu] + ggA[rb * 5 + 0][uu];
          float gj = acc[rb * 5 + 1][uu] + ggA[rb * 5 + 1][uu];
          float ga = acc[rb * 5 + 2][uu] + ggA[rb * 5 + 2][uu];
          float gb = acc[rb * 5 + 3][uu] + ggA[rb * 5 + 3][uu];
          float go = acc[rb * 5 + 4][uu] + ggA[rb * 5 + 4][uu];
          float c2 = leftA ? cA[rb][uu] : 0.f;
          float nc = c1 * sigf(ga) + c2 * sigf(gb) + sigf(gi) * tanh_fast(gj);
          float nh = tanh_fast(nc) * sigf(go);
          cA[rb][uu] = nc;
          out[(((size_t)(b0 + uu) * 32 + row0) * 32 + wA) * 128 + rg] = nh;
          hA[cur][(bl0 + uu) * 136 + rg] = f2h(nh);
        }
      }
    }

    barrier_lds();                          // guards hA/hB double buffers only
  }
}

// ---------------------------------------------------------------------------
extern "C" void kernel_launch(void* const* d_in, const int* in_sizes, int n_in,
                              void* d_out, int out_size, void* d_ws, size_t ws_size,
                              hipStream_t stream) {
  const float* x    = (const float*)d_in[0];   // [32,32,128,128]
  const float* W    = (const float*)d_in[1];   // [768,640]
  const float* bias = (const float*)d_in[2];   // [640]
  float* out = (float*)d_out;                  // [32,32,32,128]
  char* ws = (char*)d_ws;

  size_t off = 0;
  u16*   xs_h  = (u16*)(ws + off);  off += (size_t)32768 * 512 * 2;  // 33.6 MB
  u16*   xs_l  = (u16*)(ws + off);  off += (size_t)32768 * 512 * 2;  // 33.6 MB
  u16*   WxT_h = (u16*)(ws + off);  off += (size_t)640 * 512 * 2;
  u16*   WxT_l = (u16*)(ws + off);  off += (size_t)640 * 512 * 2;
  u16*   Wh16  = (u16*)(ws + off);  off += (size_t)640 * 256 * 2;    // 327 KB
  float* biasp = (float*)(ws + off); off += (size_t)640 * 4;
  float* Gp    = (float*)(ws + off); off += (size_t)1024 * 640 * 32 * 4; // 83.9 MB
  // sentinel-initialized state (contiguous 25.2 MB memset 0xFF)
  u64*   cbuf  = (u64*)(ws + off);  off += (size_t)1024 * 128 * 32 * 4;  // 16.8 MB
  u16*   hb    = (u16*)(ws + off);  off += (size_t)32768 * 128 * 2;      // 8.4 MB
  (void)ws_size;

  hipMemsetAsync(cbuf, 0xFF, (size_t)1024 * 128 * 32 * 4 + (size_t)32768 * 128 * 2, stream);
  k_wprep<<<dim3(640), dim3(256), 0, stream>>>(W, bias, WxT_h, WxT_l, Wh16, biasp);
  k_xgather<<<dim3(8192), dim3(256), 0, stream>>>(x, xs_h, xs_l);
  k_gemm_in<<<dim3(256, 5), dim3(256), 0, stream>>>(xs_h, xs_l, WxT_h, WxT_l, biasp, Gp);
  k_rec<<<dim3(32), dim3(256), 0, stream>>>(Wh16, Gp, cbuf, hb, out);
}

// Round 7
// 784.346 us; speedup vs baseline: 1.5260x; 1.1787x over previous
//
#include <hip/hip_runtime.h>

// ---------------------------------------------------------------------------
// MultiDimensionalLSTM on MI355X.
// B=32, C=32, Y=X=128, win 4x4 -> grid 32x32 cells, F=512, R=128, gates 5R=640.
// Input projection: one split-bf16 MFMA GEMM (unchanged, off critical path).
//
// R13 = R12's 2-row-band structure with the register catastrophe fixed.
// R12 post-mortem: VGPR_Count=256 (cap), 22us/superstep -> weight fragments
// spilled to scratch (demand ~480 regs vs 256 VGPR + 256 AGPR caps).
// Fix: 8 waves/block (512 thr). Each wave owns ONE 16-wide r-slice
// (8x16 = 128 r), so per-wave weights halve to Bw[5][8] = 160 regs
// (MFMA-only -> AGPR-parkable); VALU-side ~120 regs. 2x MFMA parallelism.
// Structure (validated numerically by R12, absmax 0.00390625):
//  - fp16 single-plane recurrence GEMM (h & Wh fp16, fp32 acc).
//  - Block (s,H): rows 2H,2H+1, 16 batches, ALL 640 gate cols. Superstep u:
//    B=(2H+1,u-1) then A=(2H,u). A.left/B.up/B.left intra-block (LDS dbuf +
//    register c hand-off). ONLY A.up crosses blocks -> 15 MALL hops total.
//  - B first: A's sentinel sweep (issued at superstep top) hides under B;
//    B publishes before A polls (liveness).
// Transport: proven R8 data-as-flag (relaxed sc1 at MALL, sentinel 0xFF..).
// Barrier: LDS-only (no vmcnt drain; R9 lesson).
// ---------------------------------------------------------------------------

typedef unsigned short u16;
typedef unsigned int u32;
typedef unsigned long long u64;
typedef __attribute__((ext_vector_type(8))) short short8;     // 8 x 16-bit
typedef __attribute__((ext_vector_type(8))) unsigned short us8;
typedef __attribute__((ext_vector_type(4))) float floatx4;

union Frag2 { u64 q[2]; short8 s; };

__device__ inline u16 f2bf(float f) {               // RNE fp32 -> bf16
  unsigned u = __float_as_uint(f);
  u += 0x7fffu + ((u >> 16) & 1u);
  return (u16)(u >> 16);
}
__device__ inline float bf2f(u16 v) { return __uint_as_float(((unsigned)v) << 16); }
__device__ inline u16 f2h(float f) {                // RNE fp32 -> fp16
  _Float16 h = (_Float16)f;
  return *(u16*)&h;
}

__device__ inline void async16(u16* lds, const u16* g) {
  __builtin_amdgcn_global_load_lds((const __attribute__((address_space(1))) void*)g,
                                   (__attribute__((address_space(3))) void*)lds, 16, 0, 0);
}

__device__ inline float sigf(float x) { return 1.f / (1.f + __expf(-x)); }
__device__ inline float tanh_fast(float x) { return 1.f - 2.f / (__expf(2.f * x) + 1.f); }

// Relaxed agent-scope (sc1, MALL) primitives -- the proven R8 transport.
__device__ inline u64 aload64(const u64* p) {
  return __hip_atomic_load(p, __ATOMIC_RELAXED, __HIP_MEMORY_SCOPE_AGENT);
}
__device__ inline void astore16(u16* p, u16 v) {
  __hip_atomic_store(p, v, __ATOMIC_RELAXED, __HIP_MEMORY_SCOPE_AGENT);
}
__device__ inline void astore64(u64* p, u64 v) {
  __hip_atomic_store(p, v, __ATOMIC_RELAXED, __HIP_MEMORY_SCOPE_AGENT);
}
// SWAR sentinel checks (exact; R8-proven reasoning).
__device__ inline u64 bad32(u64 v) {      // any u32 half == 0xFFFFFFFF
  u64 nv = ~v;
  return (nv - 0x0000000100000001ull) & ~nv & 0x8000000080000000ull;
}
__device__ inline u64 bad16x4(u64 v) {    // any u16 lane == 0xFFFF
  u64 nv = ~v;
  return (nv - 0x0001000100010001ull) & ~nv & 0x8000800080008000ull;
}
__device__ inline u64 packf2(float a, float b) {
  return (u64)__float_as_uint(a) | ((u64)__float_as_uint(b) << 32);
}

// LDS-only barrier: no vmcnt drain (global stores drain async; sentinel-safe).
__device__ inline void barrier_lds() {
  __builtin_amdgcn_sched_barrier(0);
  __asm__ __volatile__("s_waitcnt lgkmcnt(0)" ::: "memory");
  __builtin_amdgcn_s_barrier();
  __builtin_amdgcn_sched_barrier(0);
}

// ---------------------------------------------------------------------------
// Prep 1: W [768][640] fp32 -> WxT_{h,l} [640 pcol][512 k] (pcol = r*5+g,
// split-bf16 for the input GEMM), Wh16 [640 col][256 k] fp16 (col = g*128+r),
// biasp [640 pcol].
// ---------------------------------------------------------------------------
__global__ __launch_bounds__(256) void k_wprep(const float* __restrict__ W,
                                               const float* __restrict__ bias,
                                               u16* __restrict__ WxT_h, u16* __restrict__ WxT_l,
                                               u16* __restrict__ Wh16,
                                               float* __restrict__ biasp) {
  int pcol = blockIdx.x;                       // 0..639
  int col  = (pcol % 5) * 128 + pcol / 5;      // original gate column
  for (int k = threadIdx.x; k < 768; k += 256) {
    float v = W[(size_t)k * 640 + col];
    if (k < 512) {
      u16 hi = f2bf(v);
      WxT_h[(size_t)pcol * 512 + k] = hi;
      WxT_l[(size_t)pcol * 512 + k] = f2bf(v - bf2f(hi));
    } else {
      Wh16[(size_t)col * 256 + (k - 512)] = f2h(v);
    }
  }
  if (threadIdx.x == 0) biasp[pcol] = bias[col];
}

// ---------------------------------------------------------------------------
// Prep 2: gather x [B,C,Y,X] -> xs hi/lo [t][b][f].
// ---------------------------------------------------------------------------
__global__ __launch_bounds__(256) void k_xgather(const float* __restrict__ x,
                                                 u16* __restrict__ xs_h,
                                                 u16* __restrict__ xs_l) {
  int lane = threadIdx.x & 63;
  int pair = blockIdx.x * 4 + (threadIdx.x >> 6);  // t*32+b
  int t = pair >> 5, b = pair & 31;
  int y = t >> 3, x0 = (t & 7) * 16;
  int j = lane >> 2;
  int cbase = (lane & 3) * 8;
  const float* src = x + ((size_t)b * 32 * 128 + y) * 128 + x0 + j;
  us8 vh, vl;
#pragma unroll
  for (int u = 0; u < 8; ++u) {
    float f = src[(size_t)(cbase + u) * 16384];
    u16 hi = f2bf(f);
    vh[u] = hi;
    vl[u] = f2bf(f - bf2f(hi));
  }
  *(us8*)(xs_h + (size_t)pair * 512 + lane * 8) = vh;
  *(us8*)(xs_l + (size_t)pair * 512 + lane * 8) = vl;
}

// ---------------------------------------------------------------------------
// Input GEMM (split-bf16): M=32768, N=640, K=512. 128x128 tile, BK=32.
// Gp stored [t][pcol][32 b] (16B floatx4).
// ---------------------------------------------------------------------------
__global__ __launch_bounds__(256) void k_gemm_in(const u16* __restrict__ xs_h,
                                                 const u16* __restrict__ xs_l,
                                                 const u16* __restrict__ WxT_h,
                                                 const u16* __restrict__ WxT_l,
                                                 const float* __restrict__ biasp,
                                                 float* __restrict__ Gp) {
  __shared__ u16 Ah[128 * 32], Al[128 * 32];
  __shared__ u16 Bh[128 * 32], Bl[128 * 32];
  const int tid = threadIdx.x;
  const int wv = tid >> 6, lane = tid & 63;
  const int quad = lane >> 4, l16 = lane & 15;
  const int m0 = blockIdx.x * 128;
  const int n0 = blockIdx.y * 128;
  const int arow = lane >> 2;
  const int acol = (lane & 3) * 8;

  floatx4 acc[4][4] = {};

  for (int kt = 0; kt < 512; kt += 32) {
#pragma unroll
    for (int i = 0; i < 2; ++i) {
      int chunk = wv * 2 + i;
      int row = chunk * 16 + arow;
      size_t aoff = (size_t)(m0 + row) * 512 + kt + acol;
      size_t boff = (size_t)(n0 + row) * 512 + kt + acol;
      async16(&Ah[chunk * 512 + lane * 8], xs_h + aoff);
      async16(&Al[chunk * 512 + lane * 8], xs_l + aoff);
      async16(&Bh[chunk * 512 + lane * 8], WxT_h + boff);
      async16(&Bl[chunk * 512 + lane * 8], WxT_l + boff);
    }
    __syncthreads();
    short8 afh[4], afl[4], bfh[4], bfl[4];
#pragma unroll
    for (int mt = 0; mt < 4; ++mt) {
      int ro = ((wv & 1) * 64 + mt * 16 + l16) * 32 + quad * 8;
      afh[mt] = *(const short8*)&Ah[ro];
      afl[mt] = *(const short8*)&Al[ro];
    }
#pragma unroll
    for (int nt = 0; nt < 4; ++nt) {
      int ro = ((wv >> 1) * 64 + nt * 16 + l16) * 32 + quad * 8;
      bfh[nt] = *(const short8*)&Bh[ro];
      bfl[nt] = *(const short8*)&Bl[ro];
    }
#pragma unroll
    for (int mt = 0; mt < 4; ++mt)
#pragma unroll
      for (int nt = 0; nt < 4; ++nt) {
        floatx4 a = acc[mt][nt];
        a = __builtin_amdgcn_mfma_f32_16x16x32_bf16(afl[mt], bfh[nt], a, 0, 0, 0);
        a = __builtin_amdgcn_mfma_f32_16x16x32_bf16(afh[mt], bfl[nt], a, 0, 0, 0);
        a = __builtin_amdgcn_mfma_f32_16x16x32_bf16(afh[mt], bfh[nt], a, 0, 0, 0);
        acc[mt][nt] = a;
      }
    __syncthreads();
  }
#pragma unroll
  for (int nt = 0; nt < 4; ++nt) {
    int n = n0 + (wv >> 1) * 64 + nt * 16 + l16;
    float bv = biasp[n];
#pragma unroll
    for (int mt = 0; mt < 4; ++mt) {
      int mBase = m0 + (wv & 1) * 64 + mt * 16 + quad * 4;   // 4 consecutive m, same t
      int tt = mBase >> 5, bb = mBase & 31;
      floatx4 vv;
#pragma unroll
      for (int r = 0; r < 4; ++r) vv[r] = acc[mt][nt][r] + bv;
      *(floatx4*)&Gp[((size_t)tt * 640 + n) * 32 + bb] = vv;
    }
  }
}

// ---------------------------------------------------------------------------
// Persistent recurrence, 2-row bands, full-N blocks, fp16 GEMM, 8 waves.
// Grid 32: bid = H*2 + s (lower H first). Block 512 thr = 8 waves (2/SIMD,
// 256-reg budget/wave). Wave wv owns r-slice rg = wv*16 + l16; lane cells:
// 4 batches (b0..b0+3) x 1 r, for BOTH rows (c hand-off in registers).
// hb:  fp16 h state, [t*32+b][128 r]  (sentinel 0xFFFF = fp16 NaN).
// cbuf: fp32 c state, [t][128 r][32 b] (sentinel 0xFFFFFFFF = NaN).
// ---------------------------------------------------------------------------
__global__ __launch_bounds__(512, 1) void k_rec(const u16* __restrict__ Wh16,
                                                const float* __restrict__ Gp,
                                                u64* __restrict__ cbuf,
                                                u16* __restrict__ hb,
                                                float* __restrict__ out) {
  __shared__ u16 hA[2][16 * 136], hB[2][16 * 136];   // [buf][local b][r], pad 136

  const int s = blockIdx.x & 1, H = blockIdx.x >> 1;
  const int sb = s * 16;
  const int tid = threadIdx.x;
  const int wv = tid >> 6, lane = tid & 63;
  const int quad = lane >> 4, l16 = lane & 15;
  const int rg = wv * 16 + l16;             // this wave/lane's r
  const int b0 = sb + quad * 4;             // global batch base
  const int bl0 = quad * 4;                 // local batch base
  const int row0 = 2 * H, row1 = 2 * H + 1;
  const u64* hb64 = (const u64*)hb;

  // ---- Wh fp16 fragments -> registers, once. 160 regs/lane (MFMA-only).
  // ks 0..3 = up (k 0..127), ks 4..7 = left (k 128..255).
  short8 Bw[5][8];
#pragma unroll
  for (int g = 0; g < 5; ++g) {
    const u16* p = Wh16 + (size_t)(g * 128 + rg) * 256 + quad * 8;
#pragma unroll
    for (int ks = 0; ks < 8; ++ks)
      Bw[g][ks] = *(const short8*)(p + ks * 32);
  }

  float cA[4] = {0.f, 0.f, 0.f, 0.f};       // c of row 2H, lane's 4 cells
  float cB[4] = {0.f, 0.f, 0.f, 0.f};       // c of row 2H+1

  for (int u = 0; u <= 32; ++u) {
    const bool hasA = (u < 32), hasB = (u >= 1);
    const int wA = u, wB = u - 1;
    const int tA = row0 * 32 + wA, tB = row1 * 32 + wB;
    const bool upA = (H >= 1);              // row0: up iff H>=1 (H=0 never)
    const bool leftA = (u > 0);
    const bool upB = (H >= 1) || (u >= 2);  // faithful off-by-one at (1,0)
    const bool leftB = (u >= 2);
    const int pA = (u + 1) & 1;             // previous LDS buffer
    const int cur = u & 1;

    // ---- issue A's remote sweep (lands during B's compute) ----
    u64 uq[4][2]; u64 cq0 = 0, cq1 = 0;
    size_t ub = 0, c0 = 0;
    const bool needR = upA && hasA;
    if (needR) {
      ub = (((size_t)(tA - 32) * 32 + sb + l16) * 128 + quad * 8) >> 2;   // u64 idx
      c0 = (((size_t)(tA - 32) * 128 + rg) * 32 + b0) >> 1;
#pragma unroll
      for (int ks = 0; ks < 4; ++ks) {
        uq[ks][0] = aload64(hb64 + ub + ks * 8);
        uq[ks][1] = aload64(hb64 + ub + ks * 8 + 1);
      }
      cq0 = aload64(cbuf + c0); cq1 = aload64(cbuf + c0 + 1);
    }

    // ================= cell B = (row1, wB): all-local =================
    if (hasB) {
      floatx4 gg[5];
#pragma unroll
      for (int g = 0; g < 5; ++g)
        gg[g] = *(const floatx4*)(Gp + ((size_t)tB * 640 + rg * 5 + g) * 32 + b0);
      floatx4 acc[5] = {};
      if (upB) {                            // up = A of previous superstep (LDS)
#pragma unroll
        for (int ks = 0; ks < 4; ++ks) {
          short8 a = *(const short8*)&hA[pA][l16 * 136 + ks * 32 + quad * 8];
#pragma unroll
          for (int g = 0; g < 5; ++g)
            acc[g] = __builtin_amdgcn_mfma_f32_16x16x32_f16(a, Bw[g][ks], acc[g], 0, 0, 0);
        }
      }
      if (leftB) {                          // left = B of previous superstep (LDS)
#pragma unroll
        for (int ks = 0; ks < 4; ++ks) {
          short8 a = *(const short8*)&hB[pA][l16 * 136 + ks * 32 + quad * 8];
#pragma unroll
          for (int g = 0; g < 5; ++g)
            acc[g] = __builtin_amdgcn_mfma_f32_16x16x32_f16(a, Bw[g][4 + ks], acc[g], 0, 0, 0);
        }
      }
      // epilogue + publication (B feeds block H+1 -> MALL sentinel stores)
#pragma unroll
      for (int uu = 0; uu < 4; ++uu) {
        float gi = acc[0][uu] + gg[0][uu];
        float gj = acc[1][uu] + gg[1][uu];
        float ga = acc[2][uu] + gg[2][uu];
        float gb = acc[3][uu] + gg[3][uu];
        float go = acc[4][uu] + gg[4][uu];
        float c1 = upB ? cA[uu] : 0.f;      // register hand-off from row0
        float c2 = leftB ? cB[uu] : 0.f;
        float nc = c1 * sigf(ga) + c2 * sigf(gb) + sigf(gi) * tanh_fast(gj);
        float nh = tanh_fast(nc) * sigf(go);
        cB[uu] = nc;
        u16 hv = f2h(nh);
        astore16(hb + ((size_t)tB * 32 + b0 + uu) * 128 + rg, hv);
        out[(((size_t)(b0 + uu) * 32 + row1) * 32 + wB) * 128 + rg] = nh;
        hB[cur][(bl0 + uu) * 136 + rg] = hv;
      }
      size_t cwi = (((size_t)tB * 128 + rg) * 32 + b0) >> 1;
      astore64(cbuf + cwi,     packf2(cB[0], cB[1]));
      astore64(cbuf + cwi + 1, packf2(cB[2], cB[3]));
    }

    // ================= cell A = (row0, wA): remote up =================
    if (hasA) {
      floatx4 gg[5];
#pragma unroll
      for (int g = 0; g < 5; ++g)
        gg[g] = *(const floatx4*)(Gp + ((size_t)tA * 640 + rg * 5 + g) * 32 + b0);
      if (needR) {                          // sentinel poll (merged sweep)
        for (;;) {
          u64 bad = 0;
#pragma unroll
          for (int ks = 0; ks < 4; ++ks)
            bad |= bad16x4(uq[ks][0]) | bad16x4(uq[ks][1]);
          bad |= bad32(cq0) | bad32(cq1);
          if (!bad) break;
          __builtin_amdgcn_s_sleep(1);
          __asm__ __volatile__("" ::: "memory");
#pragma unroll
          for (int ks = 0; ks < 4; ++ks) {
            uq[ks][0] = aload64(hb64 + ub + ks * 8);
            uq[ks][1] = aload64(hb64 + ub + ks * 8 + 1);
          }
          cq0 = aload64(cbuf + c0); cq1 = aload64(cbuf + c0 + 1);
        }
      }
      floatx4 acc[5] = {};
      if (upA) {                            // up fragments straight from sweep regs
#pragma unroll
        for (int ks = 0; ks < 4; ++ks) {
          Frag2 f; f.q[0] = uq[ks][0]; f.q[1] = uq[ks][1];
#pragma unroll
          for (int g = 0; g < 5; ++g)
            acc[g] = __builtin_amdgcn_mfma_f32_16x16x32_f16(f.s, Bw[g][ks], acc[g], 0, 0, 0);
        }
      }
      if (leftA) {                          // left = own A of previous superstep
#pragma unroll
        for (int ks = 0; ks < 4; ++ks) {
          short8 a = *(const short8*)&hA[pA][l16 * 136 + ks * 32 + quad * 8];
#pragma unroll
          for (int g = 0; g < 5; ++g)
            acc[g] = __builtin_amdgcn_mfma_f32_16x16x32_f16(a, Bw[g][4 + ks], acc[g], 0, 0, 0);
        }
      }
      // epilogue (A is intra-consumed: out + LDS only, no MALL publication)
#pragma unroll
      for (int uu = 0; uu < 4; ++uu) {
        float c1 = 0.f;
        if (upA) {
          u64 q = (uu < 2) ? cq0 : cq1;
          c1 = __uint_as_float((u32)(q >> (32 * (uu & 1))));
        }
        float gi = acc[0][uu] + gg[0][uu];
        float gj = acc[1][uu] + gg[1][uu];
        float ga = acc[2][uu] + gg[2][uu];
        float gb = acc[3][uu] + gg[3][uu];
        float go = acc[4][uu] + gg[4][uu];
        float c2 = leftA ? cA[uu] : 0.f;
        float nc = c1 * sigf(ga) + c2 * sigf(gb) + sigf(gi) * tanh_fast(gj);
        float nh = tanh_fast(nc) * sigf(go);
        cA[uu] = nc;
        out[(((size_t)(b0 + uu) * 32 + row0) * 32 + wA) * 128 + rg] = nh;
        hA[cur][(bl0 + uu) * 136 + rg] = f2h(nh);
      }
    }

    barrier_lds();                          // guards hA/hB double buffers only
  }
}

// ---------------------------------------------------------------------------
extern "C" void kernel_launch(void* const* d_in, const int* in_sizes, int n_in,
                              void* d_out, int out_size, void* d_ws, size_t ws_size,
                              hipStream_t stream) {
  const float* x    = (const float*)d_in[0];   // [32,32,128,128]
  const float* W    = (const float*)d_in[1];   // [768,640]
  const float* bias = (const float*)d_in[2];   // [640]
  float* out = (float*)d_out;                  // [32,32,32,128]
  char* ws = (char*)d_ws;

  size_t off = 0;
  u16*   xs_h  = (u16*)(ws + off);  off += (size_t)32768 * 512 * 2;  // 33.6 MB
  u16*   xs_l  = (u16*)(ws + off);  off += (size_t)32768 * 512 * 2;  // 33.6 MB
  u16*   WxT_h = (u16*)(ws + off);  off += (size_t)640 * 512 * 2;
  u16*   WxT_l = (u16*)(ws + off);  off += (size_t)640 * 512 * 2;
  u16*   Wh16  = (u16*)(ws + off);  off += (size_t)640 * 256 * 2;    // 327 KB
  float* biasp = (float*)(ws + off); off += (size_t)640 * 4;
  float* Gp    = (float*)(ws + off); off += (size_t)1024 * 640 * 32 * 4; // 83.9 MB
  // sentinel-initialized state (contiguous 25.2 MB memset 0xFF)
  u64*   cbuf  = (u64*)(ws + off);  off += (size_t)1024 * 128 * 32 * 4;  // 16.8 MB
  u16*   hb    = (u16*)(ws + off);  off += (size_t)32768 * 128 * 2;      // 8.4 MB
  (void)ws_size;

  hipMemsetAsync(cbuf, 0xFF, (size_t)1024 * 128 * 32 * 4 + (size_t)32768 * 128 * 2, stream);
  k_wprep<<<dim3(640), dim3(256), 0, stream>>>(W, bias, WxT_h, WxT_l, Wh16, biasp);
  k_xgather<<<dim3(8192), dim3(256), 0, stream>>>(x, xs_h, xs_l);
  k_gemm_in<<<dim3(256, 5), dim3(256), 0, stream>>>(xs_h, xs_l, WxT_h, WxT_l, biasp, Gp);
  k_rec<<<dim3(32), dim3(512), 0, stream>>>(Wh16, Gp, cbuf, hb, out);
}

// Round 8
// 744.135 us; speedup vs baseline: 1.6085x; 1.0540x over previous
//
#include <hip/hip_runtime.h>

// ---------------------------------------------------------------------------
// MultiDimensionalLSTM on MI355X.
// B=32, C=32, Y=X=128, win 4x4 -> grid 32x32 cells, F=512, R=128, gates 5R=640.
// Input projection: one split-bf16 MFMA GEMM (unchanged, off critical path).
//
// R14 = R12's 2-row-band structure inside R8's PROVEN register envelope.
// Register ledger (hard-won): the ONLY config that ever held 320 weight
// regs/lane without spill is a 4-wave block (1 wave/SIMD): 240 VGPR + 256
// AGPR = 496 total (R8, worked). R12 (4-wave, demand ~540) spilled at the
// margin; R13 (8-wave, budget 256) spilled half its weights. Fix: R12's
// structure with demand cut to ~460:
//   - gate prefetch split per cell: gg0[5] before the cell's MFMAs (hidden),
//     gg1[5] issued after MFMAs, hidden under the rb=0 transcendental block.
//     (R12 preloaded 80 regs of gates up front -- that was the overflow.)
//   - everything else identical to R12 (numerically validated: fp16
//     single-plane recurrence, absmax unchanged at 0.00390625).
// Structure recap: grid 32 = 16 row-pairs x 2 batch-halves; block (s,H) owns
// rows 2H,2H+1, all 640 gate cols, 16 batches. Superstep u: B=(2H+1,u-1)
// then A=(2H,u). A.left/B.up/B.left intra-block (LDS dbuf + register c
// hand-off). ONLY A.up crosses blocks -> 15 MALL hops on the critical path.
// B first: A's sentinel sweep (issued at superstep top) hides under B;
// B publishes before A polls (liveness).
// Transport: proven R8 data-as-flag (relaxed sc1 at MALL, sentinel 0xFF..).
// Barrier: LDS-only (no vmcnt drain; R9 lesson).
// ---------------------------------------------------------------------------

typedef unsigned short u16;
typedef unsigned int u32;
typedef unsigned long long u64;
typedef __attribute__((ext_vector_type(8))) short short8;     // 8 x 16-bit
typedef __attribute__((ext_vector_type(8))) unsigned short us8;
typedef __attribute__((ext_vector_type(4))) float floatx4;

union Frag2 { u64 q[2]; short8 s; };

__device__ inline u16 f2bf(float f) {               // RNE fp32 -> bf16
  unsigned u = __float_as_uint(f);
  u += 0x7fffu + ((u >> 16) & 1u);
  return (u16)(u >> 16);
}
__device__ inline float bf2f(u16 v) { return __uint_as_float(((unsigned)v) << 16); }
__device__ inline u16 f2h(float f) {                // RNE fp32 -> fp16
  _Float16 h = (_Float16)f;
  return *(u16*)&h;
}

__device__ inline void async16(u16* lds, const u16* g) {
  __builtin_amdgcn_global_load_lds((const __attribute__((address_space(1))) void*)g,
                                   (__attribute__((address_space(3))) void*)lds, 16, 0, 0);
}

__device__ inline float sigf(float x) { return 1.f / (1.f + __expf(-x)); }
__device__ inline float tanh_fast(float x) { return 1.f - 2.f / (__expf(2.f * x) + 1.f); }

// Relaxed agent-scope (sc1, MALL) primitives -- the proven R8 transport.
__device__ inline u64 aload64(const u64* p) {
  return __hip_atomic_load(p, __ATOMIC_RELAXED, __HIP_MEMORY_SCOPE_AGENT);
}
__device__ inline void astore16(u16* p, u16 v) {
  __hip_atomic_store(p, v, __ATOMIC_RELAXED, __HIP_MEMORY_SCOPE_AGENT);
}
__device__ inline void astore64(u64* p, u64 v) {
  __hip_atomic_store(p, v, __ATOMIC_RELAXED, __HIP_MEMORY_SCOPE_AGENT);
}
// SWAR sentinel checks (exact; R8-proven reasoning).
__device__ inline u64 bad32(u64 v) {      // any u32 half == 0xFFFFFFFF
  u64 nv = ~v;
  return (nv - 0x0000000100000001ull) & ~nv & 0x8000000080000000ull;
}
__device__ inline u64 bad16x4(u64 v) {    // any u16 lane == 0xFFFF
  u64 nv = ~v;
  return (nv - 0x0001000100010001ull) & ~nv & 0x8000800080008000ull;
}
__device__ inline u64 packf2(float a, float b) {
  return (u64)__float_as_uint(a) | ((u64)__float_as_uint(b) << 32);
}

// LDS-only barrier: no vmcnt drain (global stores drain async; sentinel-safe).
__device__ inline void barrier_lds() {
  __builtin_amdgcn_sched_barrier(0);
  __asm__ __volatile__("s_waitcnt lgkmcnt(0)" ::: "memory");
  __builtin_amdgcn_s_barrier();
  __builtin_amdgcn_sched_barrier(0);
}

// ---------------------------------------------------------------------------
// Prep 1: W [768][640] fp32 -> WxT_{h,l} [640 pcol][512 k] (pcol = r*5+g,
// split-bf16 for the input GEMM), Wh16 [640 col][256 k] fp16 (col = g*128+r),
// biasp [640 pcol].
// ---------------------------------------------------------------------------
__global__ __launch_bounds__(256) void k_wprep(const float* __restrict__ W,
                                               const float* __restrict__ bias,
                                               u16* __restrict__ WxT_h, u16* __restrict__ WxT_l,
                                               u16* __restrict__ Wh16,
                                               float* __restrict__ biasp) {
  int pcol = blockIdx.x;                       // 0..639
  int col  = (pcol % 5) * 128 + pcol / 5;      // original gate column
  for (int k = threadIdx.x; k < 768; k += 256) {
    float v = W[(size_t)k * 640 + col];
    if (k < 512) {
      u16 hi = f2bf(v);
      WxT_h[(size_t)pcol * 512 + k] = hi;
      WxT_l[(size_t)pcol * 512 + k] = f2bf(v - bf2f(hi));
    } else {
      Wh16[(size_t)col * 256 + (k - 512)] = f2h(v);
    }
  }
  if (threadIdx.x == 0) biasp[pcol] = bias[col];
}

// ---------------------------------------------------------------------------
// Prep 2: gather x [B,C,Y,X] -> xs hi/lo [t][b][f].
// ---------------------------------------------------------------------------
__global__ __launch_bounds__(256) void k_xgather(const float* __restrict__ x,
                                                 u16* __restrict__ xs_h,
                                                 u16* __restrict__ xs_l) {
  int lane = threadIdx.x & 63;
  int pair = blockIdx.x * 4 + (threadIdx.x >> 6);  // t*32+b
  int t = pair >> 5, b = pair & 31;
  int y = t >> 3, x0 = (t & 7) * 16;
  int j = lane >> 2;
  int cbase = (lane & 3) * 8;
  const float* src = x + ((size_t)b * 32 * 128 + y) * 128 + x0 + j;
  us8 vh, vl;
#pragma unroll
  for (int u = 0; u < 8; ++u) {
    float f = src[(size_t)(cbase + u) * 16384];
    u16 hi = f2bf(f);
    vh[u] = hi;
    vl[u] = f2bf(f - bf2f(hi));
  }
  *(us8*)(xs_h + (size_t)pair * 512 + lane * 8) = vh;
  *(us8*)(xs_l + (size_t)pair * 512 + lane * 8) = vl;
}

// ---------------------------------------------------------------------------
// Input GEMM (split-bf16): M=32768, N=640, K=512. 128x128 tile, BK=32.
// Gp stored [t][pcol][32 b] (16B floatx4).
// ---------------------------------------------------------------------------
__global__ __launch_bounds__(256) void k_gemm_in(const u16* __restrict__ xs_h,
                                                 const u16* __restrict__ xs_l,
                                                 const u16* __restrict__ WxT_h,
                                                 const u16* __restrict__ WxT_l,
                                                 const float* __restrict__ biasp,
                                                 float* __restrict__ Gp) {
  __shared__ u16 Ah[128 * 32], Al[128 * 32];
  __shared__ u16 Bh[128 * 32], Bl[128 * 32];
  const int tid = threadIdx.x;
  const int wv = tid >> 6, lane = tid & 63;
  const int quad = lane >> 4, l16 = lane & 15;
  const int m0 = blockIdx.x * 128;
  const int n0 = blockIdx.y * 128;
  const int arow = lane >> 2;
  const int acol = (lane & 3) * 8;

  floatx4 acc[4][4] = {};

  for (int kt = 0; kt < 512; kt += 32) {
#pragma unroll
    for (int i = 0; i < 2; ++i) {
      int chunk = wv * 2 + i;
      int row = chunk * 16 + arow;
      size_t aoff = (size_t)(m0 + row) * 512 + kt + acol;
      size_t boff = (size_t)(n0 + row) * 512 + kt + acol;
      async16(&Ah[chunk * 512 + lane * 8], xs_h + aoff);
      async16(&Al[chunk * 512 + lane * 8], xs_l + aoff);
      async16(&Bh[chunk * 512 + lane * 8], WxT_h + boff);
      async16(&Bl[chunk * 512 + lane * 8], WxT_l + boff);
    }
    __syncthreads();
    short8 afh[4], afl[4], bfh[4], bfl[4];
#pragma unroll
    for (int mt = 0; mt < 4; ++mt) {
      int ro = ((wv & 1) * 64 + mt * 16 + l16) * 32 + quad * 8;
      afh[mt] = *(const short8*)&Ah[ro];
      afl[mt] = *(const short8*)&Al[ro];
    }
#pragma unroll
    for (int nt = 0; nt < 4; ++nt) {
      int ro = ((wv >> 1) * 64 + nt * 16 + l16) * 32 + quad * 8;
      bfh[nt] = *(const short8*)&Bh[ro];
      bfl[nt] = *(const short8*)&Bl[ro];
    }
#pragma unroll
    for (int mt = 0; mt < 4; ++mt)
#pragma unroll
      for (int nt = 0; nt < 4; ++nt) {
        floatx4 a = acc[mt][nt];
        a = __builtin_amdgcn_mfma_f32_16x16x32_bf16(afl[mt], bfh[nt], a, 0, 0, 0);
        a = __builtin_amdgcn_mfma_f32_16x16x32_bf16(afh[mt], bfl[nt], a, 0, 0, 0);
        a = __builtin_amdgcn_mfma_f32_16x16x32_bf16(afh[mt], bfh[nt], a, 0, 0, 0);
        acc[mt][nt] = a;
      }
    __syncthreads();
  }
#pragma unroll
  for (int nt = 0; nt < 4; ++nt) {
    int n = n0 + (wv >> 1) * 64 + nt * 16 + l16;
    float bv = biasp[n];
#pragma unroll
    for (int mt = 0; mt < 4; ++mt) {
      int mBase = m0 + (wv & 1) * 64 + mt * 16 + quad * 4;   // 4 consecutive m, same t
      int tt = mBase >> 5, bb = mBase & 31;
      floatx4 vv;
#pragma unroll
      for (int r = 0; r < 4; ++r) vv[r] = acc[mt][nt][r] + bv;
      *(floatx4*)&Gp[((size_t)tt * 640 + n) * 32 + bb] = vv;
    }
  }
}

// ---------------------------------------------------------------------------
// Persistent recurrence, 2-row bands, full-N blocks, fp16 GEMM, 4 waves.
// Grid 32: bid = H*2 + s (lower H first). Block 256 thr = 4 waves = 1/SIMD
// (496-reg proven envelope). Wave wv: r-slices {wv*16+l16, 64+wv*16+l16}
// (rb=0/1); lane cells: 2 rb x 4 batches (b0..b0+3), both rows (c in regs).
// hb:  fp16 h state, [t*32+b][128 r]  (sentinel 0xFFFF = fp16 NaN).
// cbuf: fp32 c state, [t][128 r][32 b] (sentinel 0xFFFFFFFF = NaN).
// ---------------------------------------------------------------------------
__global__ __launch_bounds__(256, 1) void k_rec(const u16* __restrict__ Wh16,
                                                const float* __restrict__ Gp,
                                                u64* __restrict__ cbuf,
                                                u16* __restrict__ hb,
                                                float* __restrict__ out) {
  __shared__ u16 hA[2][16 * 136], hB[2][16 * 136];   // [buf][local b][r], pad 136

  const int s = blockIdx.x & 1, H = blockIdx.x >> 1;
  const int sb = s * 16;
  const int tid = threadIdx.x;
  const int wv = tid >> 6, lane = tid & 63;
  const int quad = lane >> 4, l16 = lane & 15;
  const int rgA = wv * 16 + l16;            // rb=0 r
  const int rgB = 64 + wv * 16 + l16;       // rb=1 r
  const int b0 = sb + quad * 4;             // global batch base
  const int bl0 = quad * 4;                 // local batch base
  const int row0 = 2 * H, row1 = 2 * H + 1;
  const u64* hb64 = (const u64*)hb;

  // ---- Wh fp16 fragments -> registers, once. nt = rb*5+g; ks = k/32
  // (ks 0..3 = up k 0..127, ks 4..7 = left k 128..255). 320 regs, MFMA-only.
  short8 Bw[10][8];
#pragma unroll
  for (int rb = 0; rb < 2; ++rb)
#pragma unroll
    for (int g = 0; g < 5; ++g) {
      const u16* p = Wh16 + (size_t)(g * 128 + rb * 64 + wv * 16 + l16) * 256 + quad * 8;
#pragma unroll
      for (int ks = 0; ks < 8; ++ks)
        Bw[rb * 5 + g][ks] = *(const short8*)(p + ks * 32);
    }

  float cA[2][4] = {}, cB[2][4] = {};       // c state for rows 2H / 2H+1

  for (int u = 0; u <= 32; ++u) {
    const bool hasA = (u < 32), hasB = (u >= 1);
    const int wA = u, wB = u - 1;
    const int tA = row0 * 32 + wA, tB = row1 * 32 + wB;
    const bool upA = (H >= 1);              // row0: up iff H>=1 (H=0 never)
    const bool leftA = (u > 0);
    const bool upB = (H >= 1) || (u >= 2);  // faithful off-by-one at (1,0)
    const bool leftB = (u >= 2);
    const int pA = (u + 1) & 1;             // previous LDS buffer
    const int cur = u & 1;

    // ---- issue A's remote sweep (lands during B's compute) ----
    u64 uq[4][2]; u64 cq[4];
    size_t ub = 0, c0 = 0, c1i = 0;
    const bool needR = upA && hasA;
    if (needR) {
      ub  = (((size_t)(tA - 32) * 32 + sb + l16) * 128 + quad * 8) >> 2;   // u64 idx
      c0  = (((size_t)(tA - 32) * 128 + rgA) * 32 + b0) >> 1;
      c1i = (((size_t)(tA - 32) * 128 + rgB) * 32 + b0) >> 1;
#pragma unroll
      for (int ks = 0; ks < 4; ++ks) {
        uq[ks][0] = aload64(hb64 + ub + ks * 8);
        uq[ks][1] = aload64(hb64 + ub + ks * 8 + 1);
      }
      cq[0] = aload64(cbuf + c0);  cq[1] = aload64(cbuf + c0 + 1);
      cq[2] = aload64(cbuf + c1i); cq[3] = aload64(cbuf + c1i + 1);
    }

    // ================= cell B = (row1, wB): all-local =================
    if (hasB) {
      // rb=0 gate bias: issued before MFMAs (latency hidden under them)
      floatx4 gg0[5];
#pragma unroll
      for (int g = 0; g < 5; ++g)
        gg0[g] = *(const floatx4*)(Gp + ((size_t)tB * 640 + rgA * 5 + g) * 32 + b0);
      floatx4 acc[10] = {};
      if (upB) {                            // up = A of previous superstep (LDS)
#pragma unroll
        for (int ks = 0; ks < 4; ++ks) {
          short8 a = *(const short8*)&hA[pA][l16 * 136 + ks * 32 + quad * 8];
#pragma unroll
          for (int nt = 0; nt < 10; ++nt)
            acc[nt] = __builtin_amdgcn_mfma_f32_16x16x32_f16(a, Bw[nt][ks], acc[nt], 0, 0, 0);
        }
      }
      if (leftB) {                          // left = B of previous superstep (LDS)
#pragma unroll
        for (int ks = 0; ks < 4; ++ks) {
          short8 a = *(const short8*)&hB[pA][l16 * 136 + ks * 32 + quad * 8];
#pragma unroll
          for (int nt = 0; nt < 10; ++nt)
            acc[nt] = __builtin_amdgcn_mfma_f32_16x16x32_f16(a, Bw[nt][4 + ks], acc[nt], 0, 0, 0);
        }
      }
      // rb=1 gate bias: issued now, hidden under rb=0's transcendental block
      floatx4 gg1[5];
#pragma unroll
      for (int g = 0; g < 5; ++g)
        gg1[g] = *(const floatx4*)(Gp + ((size_t)tB * 640 + rgB * 5 + g) * 32 + b0);
      // epilogue + publication (B feeds block H+1 -> MALL sentinel stores)
#pragma unroll
      for (int rb = 0; rb < 2; ++rb) {
        const int rg = rb ? rgB : rgA;
#pragma unroll
        for (int uu = 0; uu < 4; ++uu) {
          float gi = acc[rb * 5 + 0][uu] + (rb ? gg1[0][uu] : gg0[0][uu]);
          float gj = acc[rb * 5 + 1][uu] + (rb ? gg1[1][uu] : gg0[1][uu]);
          float ga = acc[rb * 5 + 2][uu] + (rb ? gg1[2][uu] : gg0[2][uu]);
          float gb = acc[rb * 5 + 3][uu] + (rb ? gg1[3][uu] : gg0[3][uu]);
          float go = acc[rb * 5 + 4][uu] + (rb ? gg1[4][uu] : gg0[4][uu]);
          float c1 = upB ? cA[rb][uu] : 0.f;       // register hand-off from row0
          float c2 = leftB ? cB[rb][uu] : 0.f;
          float nc = c1 * sigf(ga) + c2 * sigf(gb) + sigf(gi) * tanh_fast(gj);
          float nh = tanh_fast(nc) * sigf(go);
          cB[rb][uu] = nc;
          u16 hv = f2h(nh);
          astore16(hb + ((size_t)tB * 32 + b0 + uu) * 128 + rg, hv);
          out[(((size_t)(b0 + uu) * 32 + row1) * 32 + wB) * 128 + rg] = nh;
          hB[cur][(bl0 + uu) * 136 + rg] = hv;
        }
        size_t cwi = (((size_t)tB * 128 + rg) * 32 + b0) >> 1;
        astore64(cbuf + cwi,     packf2(cB[rb][0], cB[rb][1]));
        astore64(cbuf + cwi + 1, packf2(cB[rb][2], cB[rb][3]));
      }
    }

    // ================= cell A = (row0, wA): remote up =================
    if (hasA) {
      // rb=0 gate bias first (hidden under poll + MFMAs)
      floatx4 gg0[5];
#pragma unroll
      for (int g = 0; g < 5; ++g)
        gg0[g] = *(const floatx4*)(Gp + ((size_t)tA * 640 + rgA * 5 + g) * 32 + b0);
      if (needR) {                          // sentinel poll (merged sweep)
        for (;;) {
          u64 bad = 0;
#pragma unroll
          for (int ks = 0; ks < 4; ++ks)
            bad |= bad16x4(uq[ks][0]) | bad16x4(uq[ks][1]);
          bad |= bad32(cq[0]) | bad32(cq[1]) | bad32(cq[2]) | bad32(cq[3]);
          if (!bad) break;
          __builtin_amdgcn_s_sleep(1);
          __asm__ __volatile__("" ::: "memory");
#pragma unroll
          for (int ks = 0; ks < 4; ++ks) {
            uq[ks][0] = aload64(hb64 + ub + ks * 8);
            uq[ks][1] = aload64(hb64 + ub + ks * 8 + 1);
          }
          cq[0] = aload64(cbuf + c0);  cq[1] = aload64(cbuf + c0 + 1);
          cq[2] = aload64(cbuf + c1i); cq[3] = aload64(cbuf + c1i + 1);
        }
      }
      floatx4 acc[10] = {};
      if (upA) {                            // up fragments straight from sweep regs
#pragma unroll
        for (int ks = 0; ks < 4; ++ks) {
          Frag2 f; f.q[0] = uq[ks][0]; f.q[1] = uq[ks][1];
#pragma unroll
          for (int nt = 0; nt < 10; ++nt)
            acc[nt] = __builtin_amdgcn_mfma_f32_16x16x32_f16(f.s, Bw[nt][ks], acc[nt], 0, 0, 0);
        }
      }
      if (leftA) {                          // left = own A of previous superstep
#pragma unroll
        for (int ks = 0; ks < 4; ++ks) {
          short8 a = *(const short8*)&hA[pA][l16 * 136 + ks * 32 + quad * 8];
#pragma unroll
          for (int nt = 0; nt < 10; ++nt)
            acc[nt] = __builtin_amdgcn_mfma_f32_16x16x32_f16(a, Bw[nt][4 + ks], acc[nt], 0, 0, 0);
        }
      }
      // rb=1 gate bias: issued now, hidden under rb=0's transcendental block
      floatx4 gg1[5];
#pragma unroll
      for (int g = 0; g < 5; ++g)
        gg1[g] = *(const floatx4*)(Gp + ((size_t)tA * 640 + rgB * 5 + g) * 32 + b0);
      // epilogue (A is intra-consumed: out + LDS only, no MALL publication)
#pragma unroll
      for (int rb = 0; rb < 2; ++rb) {
        const int rg = rb ? rgB : rgA;
#pragma unroll
        for (int uu = 0; uu < 4; ++uu) {
          float c1 = 0.f;
          if (upA) {
            u64 q = cq[rb * 2 + (uu >> 1)];
            c1 = __uint_as_float((u32)(q >> (32 * (uu & 1))));
          }
          float gi = acc[rb * 5 + 0][uu] + (rb ? gg1[0][uu] : gg0[0][uu]);
          float gj = acc[rb * 5 + 1][uu] + (rb ? gg1[1][uu] : gg0[1][uu]);
          float ga = acc[rb * 5 + 2][uu] + (rb ? gg1[2][uu] : gg0[2][uu]);
          float gb = acc[rb * 5 + 3][uu] + (rb ? gg1[3][uu] : gg0[3][uu]);
          float go = acc[rb * 5 + 4][uu] + (rb ? gg1[4][uu] : gg0[4][uu]);
          float c2 = leftA ? cA[rb][uu] : 0.f;
          float nc = c1 * sigf(ga) + c2 * sigf(gb) + sigf(gi) * tanh_fast(gj);
          float nh = tanh_fast(nc) * sigf(go);
          cA[rb][uu] = nc;
          out[(((size_t)(b0 + uu) * 32 + row0) * 32 + wA) * 128 + rg] = nh;
          hA[cur][(bl0 + uu) * 136 + rg] = f2h(nh);
        }
      }
    }

    barrier_lds();                          // guards hA/hB double buffers only
  }
}

// ---------------------------------------------------------------------------
extern "C" void kernel_launch(void* const* d_in, const int* in_sizes, int n_in,
                              void* d_out, int out_size, void* d_ws, size_t ws_size,
                              hipStream_t stream) {
  const float* x    = (const float*)d_in[0];   // [32,32,128,128]
  const float* W    = (const float*)d_in[1];   // [768,640]
  const float* bias = (const float*)d_in[2];   // [640]
  float* out = (float*)d_out;                  // [32,32,32,128]
  char* ws = (char*)d_ws;

  size_t off = 0;
  u16*   xs_h  = (u16*)(ws + off);  off += (size_t)32768 * 512 * 2;  // 33.6 MB
  u16*   xs_l  = (u16*)(ws + off);  off += (size_t)32768 * 512 * 2;  // 33.6 MB
  u16*   WxT_h = (u16*)(ws + off);  off += (size_t)640 * 512 * 2;
  u16*   WxT_l = (u16*)(ws + off);  off += (size_t)640 * 512 * 2;
  u16*   Wh16  = (u16*)(ws + off);  off += (size_t)640 * 256 * 2;    // 327 KB
  float* biasp = (float*)(ws + off); off += (size_t)640 * 4;
  float* Gp    = (float*)(ws + off); off += (size_t)1024 * 640 * 32 * 4; // 83.9 MB
  // sentinel-initialized state (contiguous 25.2 MB memset 0xFF)
  u64*   cbuf  = (u64*)(ws + off);  off += (size_t)1024 * 128 * 32 * 4;  // 16.8 MB
  u16*   hb    = (u16*)(ws + off);  off += (size_t)32768 * 128 * 2;      // 8.4 MB
  (void)ws_size;

  hipMemsetAsync(cbuf, 0xFF, (size_t)1024 * 128 * 32 * 4 + (size_t)32768 * 128 * 2, stream);
  k_wprep<<<dim3(640), dim3(256), 0, stream>>>(W, bias, WxT_h, WxT_l, Wh16, biasp);
  k_xgather<<<dim3(8192), dim3(256), 0, stream>>>(x, xs_h, xs_l);
  k_gemm_in<<<dim3(256, 5), dim3(256), 0, stream>>>(xs_h, xs_l, WxT_h, WxT_l, biasp, Gp);
  k_rec<<<dim3(32), dim3(256), 0, stream>>>(Wh16, Gp, cbuf, hb, out);
}

// Round 9
// 708.084 us; speedup vs baseline: 1.6904x; 1.0509x over previous
//
#include <hip/hip_runtime.h>

// ---------------------------------------------------------------------------
// MultiDimensionalLSTM on MI355X.
// B=32, C=32, Y=X=128, win 4x4 -> grid 32x32 cells, F=512, R=128, gates 5R=640.
// Input projection: one split-bf16 MFMA GEMM (unchanged, off critical path).
//
// R15 = R13 with ONE change: the gate-prefetch arrays (gg[5] per cell, 20
// regs live across every MFMA) are removed; gates are loaded AT THE EPILOGUE
// POINT instead. Register-ledger reasoning (R8/R12/R13/R14 evidence): when
// demand exceeds the per-wave budget, the allocator spills the longest-live-
// range values FIRST = the loop-invariant weight array -> catastrophic
// scratch reloads (R12 22us, R13 17.7us, R14 16.6us per superstep).
// R13's demand was ~260 vs the 256 budget (8 waves = 2 waves/SIMD). Removing
// the 20 always-live gg regs puts peak pressure ~225-230 -> ~30-reg margin,
// the first real slack since R8's proven envelope.
// Structure (numerically validated R12/R13/R14, absmax 0.00390625):
//  - fp16 single-plane recurrence GEMM (h & Wh fp16, fp32 acc).
//  - 2-row bands: grid 32 = 16 row-pairs x 2 batch-halves; block (s,H) owns
//    rows 2H,2H+1, 16 batches, all 640 gate cols. 8 waves; wave wv owns the
//    16-wide r-slice rg = wv*16+l16 (8x16 = 128 r). Superstep u:
//    B=(2H+1,u-1) then A=(2H,u). A.left/B.up/B.left intra-block (LDS dbuf +
//    register c hand-off). ONLY A.up crosses blocks -> 15 MALL hops total.
//  - B first: A's sentinel sweep (issued at superstep top) hides under B;
//    B publishes before A polls (liveness).
// Transport: proven R8 data-as-flag (relaxed sc1 at MALL, sentinel 0xFF..).
// Barrier: LDS-only (no vmcnt drain; R9 lesson).
// ---------------------------------------------------------------------------

typedef unsigned short u16;
typedef unsigned int u32;
typedef unsigned long long u64;
typedef __attribute__((ext_vector_type(8))) short short8;     // 8 x 16-bit
typedef __attribute__((ext_vector_type(8))) unsigned short us8;
typedef __attribute__((ext_vector_type(4))) float floatx4;

union Frag2 { u64 q[2]; short8 s; };

__device__ inline u16 f2bf(float f) {               // RNE fp32 -> bf16
  unsigned u = __float_as_uint(f);
  u += 0x7fffu + ((u >> 16) & 1u);
  return (u16)(u >> 16);
}
__device__ inline float bf2f(u16 v) { return __uint_as_float(((unsigned)v) << 16); }
__device__ inline u16 f2h(float f) {                // RNE fp32 -> fp16
  _Float16 h = (_Float16)f;
  return *(u16*)&h;
}

__device__ inline void async16(u16* lds, const u16* g) {
  __builtin_amdgcn_global_load_lds((const __attribute__((address_space(1))) void*)g,
                                   (__attribute__((address_space(3))) void*)lds, 16, 0, 0);
}

__device__ inline float sigf(float x) { return 1.f / (1.f + __expf(-x)); }
__device__ inline float tanh_fast(float x) { return 1.f - 2.f / (__expf(2.f * x) + 1.f); }

// Relaxed agent-scope (sc1, MALL) primitives -- the proven R8 transport.
__device__ inline u64 aload64(const u64* p) {
  return __hip_atomic_load(p, __ATOMIC_RELAXED, __HIP_MEMORY_SCOPE_AGENT);
}
__device__ inline void astore16(u16* p, u16 v) {
  __hip_atomic_store(p, v, __ATOMIC_RELAXED, __HIP_MEMORY_SCOPE_AGENT);
}
__device__ inline void astore64(u64* p, u64 v) {
  __hip_atomic_store(p, v, __ATOMIC_RELAXED, __HIP_MEMORY_SCOPE_AGENT);
}
// SWAR sentinel checks (exact; R8-proven reasoning).
__device__ inline u64 bad32(u64 v) {      // any u32 half == 0xFFFFFFFF
  u64 nv = ~v;
  return (nv - 0x0000000100000001ull) & ~nv & 0x8000000080000000ull;
}
__device__ inline u64 bad16x4(u64 v) {    // any u16 lane == 0xFFFF
  u64 nv = ~v;
  return (nv - 0x0001000100010001ull) & ~nv & 0x8000800080008000ull;
}
__device__ inline u64 packf2(float a, float b) {
  return (u64)__float_as_uint(a) | ((u64)__float_as_uint(b) << 32);
}

// LDS-only barrier: no vmcnt drain (global stores drain async; sentinel-safe).
__device__ inline void barrier_lds() {
  __builtin_amdgcn_sched_barrier(0);
  __asm__ __volatile__("s_waitcnt lgkmcnt(0)" ::: "memory");
  __builtin_amdgcn_s_barrier();
  __builtin_amdgcn_sched_barrier(0);
}

// ---------------------------------------------------------------------------
// Prep 1: W [768][640] fp32 -> WxT_{h,l} [640 pcol][512 k] (pcol = r*5+g,
// split-bf16 for the input GEMM), Wh16 [640 col][256 k] fp16 (col = g*128+r),
// biasp [640 pcol].
// ---------------------------------------------------------------------------
__global__ __launch_bounds__(256) void k_wprep(const float* __restrict__ W,
                                               const float* __restrict__ bias,
                                               u16* __restrict__ WxT_h, u16* __restrict__ WxT_l,
                                               u16* __restrict__ Wh16,
                                               float* __restrict__ biasp) {
  int pcol = blockIdx.x;                       // 0..639
  int col  = (pcol % 5) * 128 + pcol / 5;      // original gate column
  for (int k = threadIdx.x; k < 768; k += 256) {
    float v = W[(size_t)k * 640 + col];
    if (k < 512) {
      u16 hi = f2bf(v);
      WxT_h[(size_t)pcol * 512 + k] = hi;
      WxT_l[(size_t)pcol * 512 + k] = f2bf(v - bf2f(hi));
    } else {
      Wh16[(size_t)col * 256 + (k - 512)] = f2h(v);
    }
  }
  if (threadIdx.x == 0) biasp[pcol] = bias[col];
}

// ---------------------------------------------------------------------------
// Prep 2: gather x [B,C,Y,X] -> xs hi/lo [t][b][f].
// ---------------------------------------------------------------------------
__global__ __launch_bounds__(256) void k_xgather(const float* __restrict__ x,
                                                 u16* __restrict__ xs_h,
                                                 u16* __restrict__ xs_l) {
  int lane = threadIdx.x & 63;
  int pair = blockIdx.x * 4 + (threadIdx.x >> 6);  // t*32+b
  int t = pair >> 5, b = pair & 31;
  int y = t >> 3, x0 = (t & 7) * 16;
  int j = lane >> 2;
  int cbase = (lane & 3) * 8;
  const float* src = x + ((size_t)b * 32 * 128 + y) * 128 + x0 + j;
  us8 vh, vl;
#pragma unroll
  for (int u = 0; u < 8; ++u) {
    float f = src[(size_t)(cbase + u) * 16384];
    u16 hi = f2bf(f);
    vh[u] = hi;
    vl[u] = f2bf(f - bf2f(hi));
  }
  *(us8*)(xs_h + (size_t)pair * 512 + lane * 8) = vh;
  *(us8*)(xs_l + (size_t)pair * 512 + lane * 8) = vl;
}

// ---------------------------------------------------------------------------
// Input GEMM (split-bf16): M=32768, N=640, K=512. 128x128 tile, BK=32.
// Gp stored [t][pcol][32 b] (16B floatx4).
// ---------------------------------------------------------------------------
__global__ __launch_bounds__(256) void k_gemm_in(const u16* __restrict__ xs_h,
                                                 const u16* __restrict__ xs_l,
                                                 const u16* __restrict__ WxT_h,
                                                 const u16* __restrict__ WxT_l,
                                                 const float* __restrict__ biasp,
                                                 float* __restrict__ Gp) {
  __shared__ u16 Ah[128 * 32], Al[128 * 32];
  __shared__ u16 Bh[128 * 32], Bl[128 * 32];
  const int tid = threadIdx.x;
  const int wv = tid >> 6, lane = tid & 63;
  const int quad = lane >> 4, l16 = lane & 15;
  const int m0 = blockIdx.x * 128;
  const int n0 = blockIdx.y * 128;
  const int arow = lane >> 2;
  const int acol = (lane & 3) * 8;

  floatx4 acc[4][4] = {};

  for (int kt = 0; kt < 512; kt += 32) {
#pragma unroll
    for (int i = 0; i < 2; ++i) {
      int chunk = wv * 2 + i;
      int row = chunk * 16 + arow;
      size_t aoff = (size_t)(m0 + row) * 512 + kt + acol;
      size_t boff = (size_t)(n0 + row) * 512 + kt + acol;
      async16(&Ah[chunk * 512 + lane * 8], xs_h + aoff);
      async16(&Al[chunk * 512 + lane * 8], xs_l + aoff);
      async16(&Bh[chunk * 512 + lane * 8], WxT_h + boff);
      async16(&Bl[chunk * 512 + lane * 8], WxT_l + boff);
    }
    __syncthreads();
    short8 afh[4], afl[4], bfh[4], bfl[4];
#pragma unroll
    for (int mt = 0; mt < 4; ++mt) {
      int ro = ((wv & 1) * 64 + mt * 16 + l16) * 32 + quad * 8;
      afh[mt] = *(const short8*)&Ah[ro];
      afl[mt] = *(const short8*)&Al[ro];
    }
#pragma unroll
    for (int nt = 0; nt < 4; ++nt) {
      int ro = ((wv >> 1) * 64 + nt * 16 + l16) * 32 + quad * 8;
      bfh[nt] = *(const short8*)&Bh[ro];
      bfl[nt] = *(const short8*)&Bl[ro];
    }
#pragma unroll
    for (int mt = 0; mt < 4; ++mt)
#pragma unroll
      for (int nt = 0; nt < 4; ++nt) {
        floatx4 a = acc[mt][nt];
        a = __builtin_amdgcn_mfma_f32_16x16x32_bf16(afl[mt], bfh[nt], a, 0, 0, 0);
        a = __builtin_amdgcn_mfma_f32_16x16x32_bf16(afh[mt], bfl[nt], a, 0, 0, 0);
        a = __builtin_amdgcn_mfma_f32_16x16x32_bf16(afh[mt], bfh[nt], a, 0, 0, 0);
        acc[mt][nt] = a;
      }
    __syncthreads();
  }
#pragma unroll
  for (int nt = 0; nt < 4; ++nt) {
    int n = n0 + (wv >> 1) * 64 + nt * 16 + l16;
    float bv = biasp[n];
#pragma unroll
    for (int mt = 0; mt < 4; ++mt) {
      int mBase = m0 + (wv & 1) * 64 + mt * 16 + quad * 4;   // 4 consecutive m, same t
      int tt = mBase >> 5, bb = mBase & 31;
      floatx4 vv;
#pragma unroll
      for (int r = 0; r < 4; ++r) vv[r] = acc[mt][nt][r] + bv;
      *(floatx4*)&Gp[((size_t)tt * 640 + n) * 32 + bb] = vv;
    }
  }
}

// ---------------------------------------------------------------------------
// Persistent recurrence, 2-row bands, full-N blocks, fp16 GEMM, 8 waves.
// Grid 32: bid = H*2 + s (lower H first). Block 512 thr = 8 waves (2/SIMD,
// 256-reg budget/wave). Wave wv owns r-slice rg = wv*16 + l16; lane cells:
// 4 batches (b0..b0+3) x 1 r, for BOTH rows (c hand-off in registers).
// Register budget: Bw 160 (weights) + acc 20 + uq/cq 20 + frag 8 + misc ~25
// = ~233 peak. NO gate-prefetch arrays (the R13 overflow): gates loaded at
// the epilogue point, live only while acc is consumed.
// hb:  fp16 h state, [t*32+b][128 r]  (sentinel 0xFFFF = fp16 NaN).
// cbuf: fp32 c state, [t][128 r][32 b] (sentinel 0xFFFFFFFF = NaN).
// ---------------------------------------------------------------------------
__global__ __launch_bounds__(512, 1) void k_rec(const u16* __restrict__ Wh16,
                                                const float* __restrict__ Gp,
                                                u64* __restrict__ cbuf,
                                                u16* __restrict__ hb,
                                                float* __restrict__ out) {
  __shared__ u16 hA[2][16 * 136], hB[2][16 * 136];   // [buf][local b][r], pad 136

  const int s = blockIdx.x & 1, H = blockIdx.x >> 1;
  const int sb = s * 16;
  const int tid = threadIdx.x;
  const int wv = tid >> 6, lane = tid & 63;
  const int quad = lane >> 4, l16 = lane & 15;
  const int rg = wv * 16 + l16;             // this wave/lane's r
  const int b0 = sb + quad * 4;             // global batch base
  const int bl0 = quad * 4;                 // local batch base
  const int row0 = 2 * H, row1 = 2 * H + 1;
  const u64* hb64 = (const u64*)hb;

  // ---- Wh fp16 fragments -> registers, once. 160 regs/lane (MFMA-only).
  // ks 0..3 = up (k 0..127), ks 4..7 = left (k 128..255).
  short8 Bw[5][8];
#pragma unroll
  for (int g = 0; g < 5; ++g) {
    const u16* p = Wh16 + (size_t)(g * 128 + rg) * 256 + quad * 8;
#pragma unroll
    for (int ks = 0; ks < 8; ++ks)
      Bw[g][ks] = *(const short8*)(p + ks * 32);
  }

  float cA[4] = {0.f, 0.f, 0.f, 0.f};       // c of row 2H, lane's 4 cells
  float cB[4] = {0.f, 0.f, 0.f, 0.f};       // c of row 2H+1

  for (int u = 0; u <= 32; ++u) {
    const bool hasA = (u < 32), hasB = (u >= 1);
    const int wA = u, wB = u - 1;
    const int tA = row0 * 32 + wA, tB = row1 * 32 + wB;
    const bool upA = (H >= 1);              // row0: up iff H>=1 (H=0 never)
    const bool leftA = (u > 0);
    const bool upB = (H >= 1) || (u >= 2);  // faithful off-by-one at (1,0)
    const bool leftB = (u >= 2);
    const int pA = (u + 1) & 1;             // previous LDS buffer
    const int cur = u & 1;

    // ---- issue A's remote sweep (lands during B's compute) ----
    u64 uq[4][2]; u64 cq0 = 0, cq1 = 0;
    size_t ub = 0, c0 = 0;
    const bool needR = upA && hasA;
    if (needR) {
      ub = (((size_t)(tA - 32) * 32 + sb + l16) * 128 + quad * 8) >> 2;   // u64 idx
      c0 = (((size_t)(tA - 32) * 128 + rg) * 32 + b0) >> 1;
#pragma unroll
      for (int ks = 0; ks < 4; ++ks) {
        uq[ks][0] = aload64(hb64 + ub + ks * 8);
        uq[ks][1] = aload64(hb64 + ub + ks * 8 + 1);
      }
      cq0 = aload64(cbuf + c0); cq1 = aload64(cbuf + c0 + 1);
    }

    // ================= cell B = (row1, wB): all-local =================
    if (hasB) {
      floatx4 acc[5] = {};
      if (upB) {                            // up = A of previous superstep (LDS)
#pragma unroll
        for (int ks = 0; ks < 4; ++ks) {
          short8 a = *(const short8*)&hA[pA][l16 * 136 + ks * 32 + quad * 8];
#pragma unroll
          for (int g = 0; g < 5; ++g)
            acc[g] = __builtin_amdgcn_mfma_f32_16x16x32_f16(a, Bw[g][ks], acc[g], 0, 0, 0);
        }
      }
      if (leftB) {                          // left = B of previous superstep (LDS)
#pragma unroll
        for (int ks = 0; ks < 4; ++ks) {
          short8 a = *(const short8*)&hB[pA][l16 * 136 + ks * 32 + quad * 8];
#pragma unroll
          for (int g = 0; g < 5; ++g)
            acc[g] = __builtin_amdgcn_mfma_f32_16x16x32_f16(a, Bw[g][4 + ks], acc[g], 0, 0, 0);
        }
      }
      // gates loaded HERE (epilogue point): live only while acc is consumed
      const float* gpB = Gp + ((size_t)tB * 640 + rg * 5) * 32 + b0;
      floatx4 g0 = *(const floatx4*)(gpB);
      floatx4 g1 = *(const floatx4*)(gpB + 32);
      floatx4 g2 = *(const floatx4*)(gpB + 64);
      floatx4 g3 = *(const floatx4*)(gpB + 96);
      floatx4 g4 = *(const floatx4*)(gpB + 128);
      // epilogue + publication (B feeds block H+1 -> MALL sentinel stores)
#pragma unroll
      for (int uu = 0; uu < 4; ++uu) {
        float gi = acc[0][uu] + g0[uu];
        float gj = acc[1][uu] + g1[uu];
        float ga = acc[2][uu] + g2[uu];
        float gb = acc[3][uu] + g3[uu];
        float go = acc[4][uu] + g4[uu];
        float c1 = upB ? cA[uu] : 0.f;      // register hand-off from row0
        float c2 = leftB ? cB[uu] : 0.f;
        float nc = c1 * sigf(ga) + c2 * sigf(gb) + sigf(gi) * tanh_fast(gj);
        float nh = tanh_fast(nc) * sigf(go);
        cB[uu] = nc;
        u16 hv = f2h(nh);
        astore16(hb + ((size_t)tB * 32 + b0 + uu) * 128 + rg, hv);
        out[(((size_t)(b0 + uu) * 32 + row1) * 32 + wB) * 128 + rg] = nh;
        hB[cur][(bl0 + uu) * 136 + rg] = hv;
      }
      size_t cwi = (((size_t)tB * 128 + rg) * 32 + b0) >> 1;
      astore64(cbuf + cwi,     packf2(cB[0], cB[1]));
      astore64(cbuf + cwi + 1, packf2(cB[2], cB[3]));
    }

    // ================= cell A = (row0, wA): remote up =================
    if (hasA) {
      if (needR) {                          // sentinel poll (merged sweep)
        for (;;) {
          u64 bad = 0;
#pragma unroll
          for (int ks = 0; ks < 4; ++ks)
            bad |= bad16x4(uq[ks][0]) | bad16x4(uq[ks][1]);
          bad |= bad32(cq0) | bad32(cq1);
          if (!bad) break;
          __builtin_amdgcn_s_sleep(1);
          __asm__ __volatile__("" ::: "memory");
#pragma unroll
          for (int ks = 0; ks < 4; ++ks) {
            uq[ks][0] = aload64(hb64 + ub + ks * 8);
            uq[ks][1] = aload64(hb64 + ub + ks * 8 + 1);
          }
          cq0 = aload64(cbuf + c0); cq1 = aload64(cbuf + c0 + 1);
        }
      }
      floatx4 acc[5] = {};
      if (upA) {                            // up fragments straight from sweep regs
#pragma unroll
        for (int ks = 0; ks < 4; ++ks) {
          Frag2 f; f.q[0] = uq[ks][0]; f.q[1] = uq[ks][1];
#pragma unroll
          for (int g = 0; g < 5; ++g)
            acc[g] = __builtin_amdgcn_mfma_f32_16x16x32_f16(f.s, Bw[g][ks], acc[g], 0, 0, 0);
        }
      }
      if (leftA) {                          // left = own A of previous superstep
#pragma unroll
        for (int ks = 0; ks < 4; ++ks) {
          short8 a = *(const short8*)&hA[pA][l16 * 136 + ks * 32 + quad * 8];
#pragma unroll
          for (int g = 0; g < 5; ++g)
            acc[g] = __builtin_amdgcn_mfma_f32_16x16x32_f16(a, Bw[g][4 + ks], acc[g], 0, 0, 0);
        }
      }
      // gates loaded HERE (epilogue point)
      const float* gpA = Gp + ((size_t)tA * 640 + rg * 5) * 32 + b0;
      floatx4 g0 = *(const floatx4*)(gpA);
      floatx4 g1 = *(const floatx4*)(gpA + 32);
      floatx4 g2 = *(const floatx4*)(gpA + 64);
      floatx4 g3 = *(const floatx4*)(gpA + 96);
      floatx4 g4 = *(const floatx4*)(gpA + 128);
      // epilogue (A is intra-consumed: out + LDS only, no MALL publication)
#pragma unroll
      for (int uu = 0; uu < 4; ++uu) {
        float c1 = 0.f;
        if (upA) {
          u64 q = (uu < 2) ? cq0 : cq1;
          c1 = __uint_as_float((u32)(q >> (32 * (uu & 1))));
        }
        float gi = acc[0][uu] + g0[uu];
        float gj = acc[1][uu] + g1[uu];
        float ga = acc[2][uu] + g2[uu];
        float gb = acc[3][uu] + g3[uu];
        float go = acc[4][uu] + g4[uu];
        float c2 = leftA ? cA[uu] : 0.f;
        float nc = c1 * sigf(ga) + c2 * sigf(gb) + sigf(gi) * tanh_fast(gj);
        float nh = tanh_fast(nc) * sigf(go);
        cA[uu] = nc;
        out[(((size_t)(b0 + uu) * 32 + row0) * 32 + wA) * 128 + rg] = nh;
        hA[cur][(bl0 + uu) * 136 + rg] = f2h(nh);
      }
    }

    barrier_lds();                          // guards hA/hB double buffers only
  }
}

// ---------------------------------------------------------------------------
extern "C" void kernel_launch(void* const* d_in, const int* in_sizes, int n_in,
                              void* d_out, int out_size, void* d_ws, size_t ws_size,
                              hipStream_t stream) {
  const float* x    = (const float*)d_in[0];   // [32,32,128,128]
  const float* W    = (const float*)d_in[1];   // [768,640]
  const float* bias = (const float*)d_in[2];   // [640]
  float* out = (float*)d_out;                  // [32,32,32,128]
  char* ws = (char*)d_ws;

  size_t off = 0;
  u16*   xs_h  = (u16*)(ws + off);  off += (size_t)32768 * 512 * 2;  // 33.6 MB
  u16*   xs_l  = (u16*)(ws + off);  off += (size_t)32768 * 512 * 2;  // 33.6 MB
  u16*   WxT_h = (u16*)(ws + off);  off += (size_t)640 * 512 * 2;
  u16*   WxT_l = (u16*)(ws + off);  off += (size_t)640 * 512 * 2;
  u16*   Wh16  = (u16*)(ws + off);  off += (size_t)640 * 256 * 2;    // 327 KB
  float* biasp = (float*)(ws + off); off += (size_t)640 * 4;
  float* Gp    = (float*)(ws + off); off += (size_t)1024 * 640 * 32 * 4; // 83.9 MB
  // sentinel-initialized state (contiguous 25.2 MB memset 0xFF)
  u64*   cbuf  = (u64*)(ws + off);  off += (size_t)1024 * 128 * 32 * 4;  // 16.8 MB
  u16*   hb    = (u16*)(ws + off);  off += (size_t)32768 * 128 * 2;      // 8.4 MB
  (void)ws_size;

  hipMemsetAsync(cbuf, 0xFF, (size_t)1024 * 128 * 32 * 4 + (size_t)32768 * 128 * 2, stream);
  k_wprep<<<dim3(640), dim3(256), 0, stream>>>(W, bias, WxT_h, WxT_l, Wh16, biasp);
  k_xgather<<<dim3(8192), dim3(256), 0, stream>>>(x, xs_h, xs_l);
  k_gemm_in<<<dim3(256, 5), dim3(256), 0, stream>>>(xs_h, xs_l, WxT_h, WxT_l, biasp, Gp);
  k_rec<<<dim3(32), dim3(512), 0, stream>>>(Wh16, Gp, cbuf, hb, out);
}

// Round 10
// 443.539 us; speedup vs baseline: 2.6986x; 1.5964x over previous
//
#include <hip/hip_runtime.h>

// ---------------------------------------------------------------------------
// MultiDimensionalLSTM on MI355X.
// B=32, C=32, Y=X=128, win 4x4 -> grid 32x32 cells, F=512, R=128, gates 5R=640.
// Input projection: one split-bf16 MFMA GEMM (off critical path).
//
// R16 = R8 (the measured-best recurrence schedule, 375us) + two individually
// validated upgrades, nothing else:
//  (a) fp16 single-plane recurrence GEMM (h & Wh fp16, fp32 acc) -- validated
//      numerically in R12-R15 (absmax pinned at 0.00390625 across 4 passes).
//      120 -> 40 MFMAs/step, sweep 16 -> 10 u64, weights 320 -> 160 regs in
//      R8's proven 4-wave envelope (now with huge slack instead of margin).
//  (b) LDS-only barrier (correctness-proven R11-R15): removes the per-step
//      s_waitcnt vmcnt(0) drain R8's __syncthreads imposed.
// Register ledger (R12-R15 closed): 2-wave/SIMD configs cap at 128 VGPR ->
// register-resident full-N weights are unreachable; 4-wave 1/SIMD holds
// 320+110 (R8). Full-N banding abandoned on evidence.
// Geometry (R8): grid 128: bid = h*4 + s*2 + hf. Block 256 thr = 4 waves.
// Block (s,hf,h): batches sb..sb+16, r in [hf*64,+64). Wave wv: r0 = hf*64 +
// wv*16; lane (quad,l16): r = r0+l16, batches b0..b0+3. Gate-major weight
// tiles: tile g covers Wh cols g*128+r -> all 5 gates of a cell land in one
// lane -> in-register epilogue. Per step: ONE merged remote sweep (up 8 +
// sib 4 + c 2 u64) overlapped with 10 own-left MFMAs from LDS; then 30
// remote-dep MFMAs; in-register epilogue; 1 LDS barrier.
// Transport: proven R8 data-as-flag (relaxed sc1 at MALL, sentinel 0xFF..
// = fp16/fp32 NaN patterns, unreachable for tanh/sig outputs).
// ---------------------------------------------------------------------------

typedef unsigned short u16;
typedef unsigned int u32;
typedef unsigned long long u64;
typedef __attribute__((ext_vector_type(8))) short short8;     // 8 x 16-bit
typedef __attribute__((ext_vector_type(8))) unsigned short us8;
typedef __attribute__((ext_vector_type(4))) float floatx4;

union Frag2 { u64 q[2]; short8 s; };

__device__ inline u16 f2bf(float f) {               // RNE fp32 -> bf16
  unsigned u = __float_as_uint(f);
  u += 0x7fffu + ((u >> 16) & 1u);
  return (u16)(u >> 16);
}
__device__ inline float bf2f(u16 v) { return __uint_as_float(((unsigned)v) << 16); }
__device__ inline u16 f2h(float f) {                // RNE fp32 -> fp16
  _Float16 h = (_Float16)f;
  return *(u16*)&h;
}

__device__ inline void async16(u16* lds, const u16* g) {
  __builtin_amdgcn_global_load_lds((const __attribute__((address_space(1))) void*)g,
                                   (__attribute__((address_space(3))) void*)lds, 16, 0, 0);
}

__device__ inline float sigf(float x) { return 1.f / (1.f + __expf(-x)); }
__device__ inline float tanh_fast(float x) { return 1.f - 2.f / (__expf(2.f * x) + 1.f); }

// Relaxed agent-scope (sc1, MALL) primitives -- the proven R8 transport.
__device__ inline u64 aload64(const u64* p) {
  return __hip_atomic_load(p, __ATOMIC_RELAXED, __HIP_MEMORY_SCOPE_AGENT);
}
__device__ inline void astore16(u16* p, u16 v) {
  __hip_atomic_store(p, v, __ATOMIC_RELAXED, __HIP_MEMORY_SCOPE_AGENT);
}
__device__ inline void astore64(u64* p, u64 v) {
  __hip_atomic_store(p, v, __ATOMIC_RELAXED, __HIP_MEMORY_SCOPE_AGENT);
}
// SWAR sentinel checks (exact; R8-proven reasoning).
__device__ inline u64 bad32(u64 v) {      // any u32 half == 0xFFFFFFFF
  u64 nv = ~v;
  return (nv - 0x0000000100000001ull) & ~nv & 0x8000000080000000ull;
}
__device__ inline u64 bad16x4(u64 v) {    // any u16 lane == 0xFFFF
  u64 nv = ~v;
  return (nv - 0x0001000100010001ull) & ~nv & 0x8000800080008000ull;
}
__device__ inline u64 packf2(float a, float b) {
  return (u64)__float_as_uint(a) | ((u64)__float_as_uint(b) << 32);
}

// LDS-only barrier: no vmcnt drain (global stores drain async; sentinel-safe).
__device__ inline void barrier_lds() {
  __builtin_amdgcn_sched_barrier(0);
  __asm__ __volatile__("s_waitcnt lgkmcnt(0)" ::: "memory");
  __builtin_amdgcn_s_barrier();
  __builtin_amdgcn_sched_barrier(0);
}

// ---------------------------------------------------------------------------
// Prep 1: W [768][640] fp32 -> WxT_{h,l} [640 pcol][512 k] (pcol = r*5+g,
// split-bf16 for the input GEMM), Wh16 [640 col][256 k] fp16 (col = g*128+r),
// biasp [640 pcol].
// ---------------------------------------------------------------------------
__global__ __launch_bounds__(256) void k_wprep(const float* __restrict__ W,
                                               const float* __restrict__ bias,
                                               u16* __restrict__ WxT_h, u16* __restrict__ WxT_l,
                                               u16* __restrict__ Wh16,
                                               float* __restrict__ biasp) {
  int pcol = blockIdx.x;                       // 0..639
  int col  = (pcol % 5) * 128 + pcol / 5;      // original gate column
  for (int k = threadIdx.x; k < 768; k += 256) {
    float v = W[(size_t)k * 640 + col];
    if (k < 512) {
      u16 hi = f2bf(v);
      WxT_h[(size_t)pcol * 512 + k] = hi;
      WxT_l[(size_t)pcol * 512 + k] = f2bf(v - bf2f(hi));
    } else {
      Wh16[(size_t)col * 256 + (k - 512)] = f2h(v);
    }
  }
  if (threadIdx.x == 0) biasp[pcol] = bias[col];
}

// ---------------------------------------------------------------------------
// Prep 2: gather x [B,C,Y,X] -> xs hi/lo [t][b][f].
// ---------------------------------------------------------------------------
__global__ __launch_bounds__(256) void k_xgather(const float* __restrict__ x,
                                                 u16* __restrict__ xs_h,
                                                 u16* __restrict__ xs_l) {
  int lane = threadIdx.x & 63;
  int pair = blockIdx.x * 4 + (threadIdx.x >> 6);  // t*32+b
  int t = pair >> 5, b = pair & 31;
  int y = t >> 3, x0 = (t & 7) * 16;
  int j = lane >> 2;
  int cbase = (lane & 3) * 8;
  const float* src = x + ((size_t)b * 32 * 128 + y) * 128 + x0 + j;
  us8 vh, vl;
#pragma unroll
  for (int u = 0; u < 8; ++u) {
    float f = src[(size_t)(cbase + u) * 16384];
    u16 hi = f2bf(f);
    vh[u] = hi;
    vl[u] = f2bf(f - bf2f(hi));
  }
  *(us8*)(xs_h + (size_t)pair * 512 + lane * 8) = vh;
  *(us8*)(xs_l + (size_t)pair * 512 + lane * 8) = vl;
}

// ---------------------------------------------------------------------------
// Input GEMM (split-bf16): M=32768, N=640, K=512. 128x128 tile, BK=32.
// Gp stored [t][pcol][32 b] (16B floatx4).
// ---------------------------------------------------------------------------
__global__ __launch_bounds__(256) void k_gemm_in(const u16* __restrict__ xs_h,
                                                 const u16* __restrict__ xs_l,
                                                 const u16* __restrict__ WxT_h,
                                                 const u16* __restrict__ WxT_l,
                                                 const float* __restrict__ biasp,
                                                 float* __restrict__ Gp) {
  __shared__ u16 Ah[128 * 32], Al[128 * 32];
  __shared__ u16 Bh[128 * 32], Bl[128 * 32];
  const int tid = threadIdx.x;
  const int wv = tid >> 6, lane = tid & 63;
  const int quad = lane >> 4, l16 = lane & 15;
  const int m0 = blockIdx.x * 128;
  const int n0 = blockIdx.y * 128;
  const int arow = lane >> 2;
  const int acol = (lane & 3) * 8;

  floatx4 acc[4][4] = {};

  for (int kt = 0; kt < 512; kt += 32) {
#pragma unroll
    for (int i = 0; i < 2; ++i) {
      int chunk = wv * 2 + i;
      int row = chunk * 16 + arow;
      size_t aoff = (size_t)(m0 + row) * 512 + kt + acol;
      size_t boff = (size_t)(n0 + row) * 512 + kt + acol;
      async16(&Ah[chunk * 512 + lane * 8], xs_h + aoff);
      async16(&Al[chunk * 512 + lane * 8], xs_l + aoff);
      async16(&Bh[chunk * 512 + lane * 8], WxT_h + boff);
      async16(&Bl[chunk * 512 + lane * 8], WxT_l + boff);
    }
    __syncthreads();
    short8 afh[4], afl[4], bfh[4], bfl[4];
#pragma unroll
    for (int mt = 0; mt < 4; ++mt) {
      int ro = ((wv & 1) * 64 + mt * 16 + l16) * 32 + quad * 8;
      afh[mt] = *(const short8*)&Ah[ro];
      afl[mt] = *(const short8*)&Al[ro];
    }
#pragma unroll
    for (int nt = 0; nt < 4; ++nt) {
      int ro = ((wv >> 1) * 64 + nt * 16 + l16) * 32 + quad * 8;
      bfh[nt] = *(const short8*)&Bh[ro];
      bfl[nt] = *(const short8*)&Bl[ro];
    }
#pragma unroll
    for (int mt = 0; mt < 4; ++mt)
#pragma unroll
      for (int nt = 0; nt < 4; ++nt) {
        floatx4 a = acc[mt][nt];
        a = __builtin_amdgcn_mfma_f32_16x16x32_bf16(afl[mt], bfh[nt], a, 0, 0, 0);
        a = __builtin_amdgcn_mfma_f32_16x16x32_bf16(afh[mt], bfl[nt], a, 0, 0, 0);
        a = __builtin_amdgcn_mfma_f32_16x16x32_bf16(afh[mt], bfh[nt], a, 0, 0, 0);
        acc[mt][nt] = a;
      }
    __syncthreads();
  }
#pragma unroll
  for (int nt = 0; nt < 4; ++nt) {
    int n = n0 + (wv >> 1) * 64 + nt * 16 + l16;
    float bv = biasp[n];
#pragma unroll
    for (int mt = 0; mt < 4; ++mt) {
      int mBase = m0 + (wv & 1) * 64 + mt * 16 + quad * 4;   // 4 consecutive m, same t
      int tt = mBase >> 5, bb = mBase & 31;
      floatx4 vv;
#pragma unroll
      for (int r = 0; r < 4; ++r) vv[r] = acc[mt][nt][r] + bv;
      *(floatx4*)&Gp[((size_t)tt * 640 + n) * 32 + bb] = vv;
    }
  }
}

// ---------------------------------------------------------------------------
// Persistent recurrence (R8 schedule, fp16). Grid 128: bid = h*4 + s*2 + hf.
// Block 256 thr = 4 waves = 1 wave/SIMD (proven 496-reg envelope; weights
// now only 160 regs -> large slack). ks slots: 0..3 up (k 0..127),
// 4..5 own-left (k 128+hf*64+..), 6..7 sib (k 128+(1-hf)*64+..).
// hb: fp16 h, [t*32+b][128 r] (sentinel 0xFFFF). cbuf: fp32 c,
// [t][128 r][32 b] (sentinel 0xFFFFFFFF).
// ---------------------------------------------------------------------------
__global__ __launch_bounds__(256, 1) void k_rec(const u16* __restrict__ Wh16,
                                                const float* __restrict__ Gp,
                                                u64* __restrict__ cbuf,
                                                u16* __restrict__ hb,
                                                float* __restrict__ out) {
  __shared__ u16 h2[2][1024];                 // [buf][16 b][64 own-r], XOR-swizzled

  const int hf = blockIdx.x & 1;
  const int s  = (blockIdx.x >> 1) & 1;
  const int h  = blockIdx.x >> 2;
  const int sb = s * 16;
  const int tid = threadIdx.x;
  const int wv = tid >> 6, lane = tid & 63;
  const int quad = lane >> 4, l16 = lane & 15;
  const int rg = hf * 64 + wv * 16 + l16;     // this lane's r
  const int b0 = sb + quad * 4;               // this lane's batch base
  const u64* hb64 = (const u64*)hb;

  // ---- Wh fp16 fragments -> registers, once. 160 regs/lane, static index.
  short8 Bw[5][8];
#pragma unroll
  for (int g = 0; g < 5; ++g) {
    const u16* p = Wh16 + (size_t)(g * 128 + rg) * 256 + quad * 8;
#pragma unroll
    for (int ks = 0; ks < 8; ++ks) {
      int kk;
      if (ks < 4)      kk = ks * 32;
      else if (ks < 6) kk = 128 + hf * 64 + (ks - 4) * 32;
      else             kk = 128 + (1 - hf) * 64 + (ks - 6) * 32;
      Bw[g][ks] = *(const short8*)(p + kk);
    }
  }

  float cl[4] = {0.f, 0.f, 0.f, 0.f};         // c_left, this lane's 4 cells

  for (int w = 0; w < 32; ++w) {
    const int t = h * 32 + w;
    const bool upok = t > 32;                 // faithful off-by-one
    const bool leftok = w > 0;

    // gate biases (plain cached loads; in flight during sweep/poll)
    floatx4 gg[5];
    {
      const float* gpb = Gp + ((size_t)t * 640 + rg * 5) * 32 + b0;
#pragma unroll
      for (int g = 0; g < 5; ++g) gg[g] = *(const floatx4*)(gpb + g * 32);
    }

    // ---- issue merged remote sweep ----
    u64 uq[4][2]; u64 sq[2][2]; u64 cq0 = 0, cq1 = 0;
    size_t ub = 0, sbase = 0, cb = 0;
    if (upok) {
      ub = (((size_t)(t - 32) * 32 + sb + l16) * 128 + quad * 8) >> 2;   // u64 idx
      cb = (((size_t)(t - 32) * 128 + rg) * 32 + b0) >> 1;
#pragma unroll
      for (int ks = 0; ks < 4; ++ks) {
        uq[ks][0] = aload64(hb64 + ub + ks * 8);
        uq[ks][1] = aload64(hb64 + ub + ks * 8 + 1);
      }
      cq0 = aload64(cbuf + cb); cq1 = aload64(cbuf + cb + 1);
    }
    if (leftok) {
      sbase = (((size_t)(t - 1) * 32 + sb + l16) * 128 + (1 - hf) * 64 + quad * 8) >> 2;
#pragma unroll
      for (int j = 0; j < 2; ++j) {
        sq[j][0] = aload64(hb64 + sbase + j * 8);
        sq[j][1] = aload64(hb64 + sbase + j * 8 + 1);
      }
    }

    floatx4 acc[5] = {};

    // ---- phase A: own-left MFMAs from LDS (hide the remote RT) ----
    if (leftok) {
      const int bsel = (w - 1) & 1;
#pragma unroll
      for (int j = 0; j < 2; ++j) {
        int idx = (l16 * 64 + j * 32 + quad * 8) ^ ((l16 & 7) << 3);
        short8 a = *(const short8*)&h2[bsel][idx];
#pragma unroll
        for (int g = 0; g < 5; ++g)
          acc[g] = __builtin_amdgcn_mfma_f32_16x16x32_f16(a, Bw[g][4 + j], acc[g], 0, 0, 0);
      }
    }

    // ---- poll: one detect for all remote deps ----
    if (upok | (int)leftok) {
      for (;;) {
        u64 bad = 0;
        if (upok) {
#pragma unroll
          for (int ks = 0; ks < 4; ++ks) bad |= bad16x4(uq[ks][0]) | bad16x4(uq[ks][1]);
          bad |= bad32(cq0) | bad32(cq1);
        }
        if (leftok) {
#pragma unroll
          for (int j = 0; j < 2; ++j) bad |= bad16x4(sq[j][0]) | bad16x4(sq[j][1]);
        }
        if (!bad) break;
        __builtin_amdgcn_s_sleep(1);
        __asm__ __volatile__("" ::: "memory");
        if (upok) {
#pragma unroll
          for (int ks = 0; ks < 4; ++ks) {
            uq[ks][0] = aload64(hb64 + ub + ks * 8);
            uq[ks][1] = aload64(hb64 + ub + ks * 8 + 1);
          }
          cq0 = aload64(cbuf + cb); cq1 = aload64(cbuf + cb + 1);
        }
        if (leftok) {
#pragma unroll
          for (int j = 0; j < 2; ++j) {
            sq[j][0] = aload64(hb64 + sbase + j * 8);
            sq[j][1] = aload64(hb64 + sbase + j * 8 + 1);
          }
        }
      }
    }

    // ---- phase B: remote-dep MFMAs ----
    if (upok) {
#pragma unroll
      for (int ks = 0; ks < 4; ++ks) {
        Frag2 f; f.q[0] = uq[ks][0]; f.q[1] = uq[ks][1];
#pragma unroll
        for (int g = 0; g < 5; ++g)
          acc[g] = __builtin_amdgcn_mfma_f32_16x16x32_f16(f.s, Bw[g][ks], acc[g], 0, 0, 0);
      }
    }
    if (leftok) {
#pragma unroll
      for (int j = 0; j < 2; ++j) {
        Frag2 f; f.q[0] = sq[j][0]; f.q[1] = sq[j][1];
#pragma unroll
        for (int g = 0; g < 5; ++g)
          acc[g] = __builtin_amdgcn_mfma_f32_16x16x32_f16(f.s, Bw[g][6 + j], acc[g], 0, 0, 0);
      }
    }

    // ---- in-register epilogue: lane's 4 cells (b0+u, rg) ----
    float c1v[4];
    c1v[0] = __uint_as_float((u32)cq0); c1v[1] = __uint_as_float((u32)(cq0 >> 32));
    c1v[2] = __uint_as_float((u32)cq1); c1v[3] = __uint_as_float((u32)(cq1 >> 32));
    const int cur = w & 1;
#pragma unroll
    for (int u = 0; u < 4; ++u) {
      float gi = acc[0][u] + gg[0][u];
      float gj = acc[1][u] + gg[1][u];
      float ga = acc[2][u] + gg[2][u];
      float gb = acc[3][u] + gg[3][u];
      float go = acc[4][u] + gg[4][u];
      float c1 = upok ? c1v[u] : 0.f;
      float c2 = leftok ? cl[u] : 0.f;
      float nc = c1 * sigf(ga) + c2 * sigf(gb) + sigf(gi) * tanh_fast(gj);
      float nh = tanh_fast(nc) * sigf(go);
      cl[u] = nc;
      u16 hv = f2h(nh);
      astore16(hb + ((size_t)t * 32 + b0 + u) * 128 + rg, hv);       // sentinel publish
      out[(((size_t)(b0 + u) * 32 + h) * 32 + w) * 128 + rg] = nh;   // plain
      int bl = quad * 4 + u;
      h2[cur][(bl * 64 + wv * 16 + l16) ^ ((bl & 7) << 3)] = hv;     // own-half LDS
    }
    size_t cw = (((size_t)t * 128 + rg) * 32 + b0) >> 1;
    astore64(cbuf + cw,     packf2(cl[0], cl[1]));
    astore64(cbuf + cw + 1, packf2(cl[2], cl[3]));

    barrier_lds();   // LDS-only: no vmcnt drain on the critical path
  }
}

// ---------------------------------------------------------------------------
extern "C" void kernel_launch(void* const* d_in, const int* in_sizes, int n_in,
                              void* d_out, int out_size, void* d_ws, size_t ws_size,
                              hipStream_t stream) {
  const float* x    = (const float*)d_in[0];   // [32,32,128,128]
  const float* W    = (const float*)d_in[1];   // [768,640]
  const float* bias = (const float*)d_in[2];   // [640]
  float* out = (float*)d_out;                  // [32,32,32,128]
  char* ws = (char*)d_ws;

  size_t off = 0;
  u16*   xs_h  = (u16*)(ws + off);  off += (size_t)32768 * 512 * 2;  // 33.6 MB
  u16*   xs_l  = (u16*)(ws + off);  off += (size_t)32768 * 512 * 2;  // 33.6 MB
  u16*   WxT_h = (u16*)(ws + off);  off += (size_t)640 * 512 * 2;
  u16*   WxT_l = (u16*)(ws + off);  off += (size_t)640 * 512 * 2;
  u16*   Wh16  = (u16*)(ws + off);  off += (size_t)640 * 256 * 2;    // 327 KB
  float* biasp = (float*)(ws + off); off += (size_t)640 * 4;
  float* Gp    = (float*)(ws + off); off += (size_t)1024 * 640 * 32 * 4; // 83.9 MB
  // sentinel-initialized state (contiguous 25.2 MB memset 0xFF)
  u64*   cbuf  = (u64*)(ws + off);  off += (size_t)1024 * 128 * 32 * 4;  // 16.8 MB
  u16*   hb    = (u16*)(ws + off);  off += (size_t)32768 * 128 * 2;      // 8.4 MB
  (void)ws_size;

  hipMemsetAsync(cbuf, 0xFF, (size_t)1024 * 128 * 32 * 4 + (size_t)32768 * 128 * 2, stream);
  k_wprep<<<dim3(640), dim3(256), 0, stream>>>(W, bias, WxT_h, WxT_l, Wh16, biasp);
  k_xgather<<<dim3(8192), dim3(256), 0, stream>>>(x, xs_h, xs_l);
  k_gemm_in<<<dim3(256, 5), dim3(256), 0, stream>>>(xs_h, xs_l, WxT_h, WxT_l, biasp, Gp);
  k_rec<<<dim3(128), dim3(256), 0, stream>>>(Wh16, Gp, cbuf, hb, out);
}

// Round 11
// 396.714 us; speedup vs baseline: 3.0171x; 1.1180x over previous
//
#include <hip/hip_runtime.h>

// ---------------------------------------------------------------------------
// MultiDimensionalLSTM on MI355X.
// B=32, C=32, Y=X=128, win 4x4 -> grid 32x32 cells, F=512, R=128, gates 5R=640.
//
// R17 = R16 (best: 443us total, k_rec 241us, no spill) with the INPUT PATH
// moved to fp16 single-plane, matching the (5-round-validated) fp16
// recurrence precision:
//  - xgather writes ONE fp16 plane (was split-bf16 hi+lo): 67->34 MB.
//  - input GEMM: 1 MFMA per tile (was 3), LDS staging 32->16 KB,
//    A-read traffic 336->168 MB. Gate error adds ~4e-4 RMS, an order below
//    the 0.0039 absmax floor (dominated by the fp16 recurrence).
//  - k_rec: IDENTICAL to R16 except epilogue store ORDER: all sentinel
//    publications (hb, cbuf) issue before the out/LDS writes, so the store
//    queue drains the consumer-visible words first (earlier detect).
// k_rec structure (R16, measured 3.8us/stage = ~3.3 intrinsic MALL hop):
// grid 128 = (h, s, hf); 4-wave blocks (1 wave/SIMD, proven no-spill
// envelope, VGPR 148); gate-major fp16 weights in registers (160/lane);
// merged sentinel sweep overlapped with own-left LDS MFMAs; in-register
// epilogue; LDS-only barrier (no vmcnt drain). Transport: relaxed sc1
// data-as-flag at MALL, sentinel 0xFF.. (NaN patterns, unreachable).
// ---------------------------------------------------------------------------

typedef unsigned short u16;
typedef unsigned int u32;
typedef unsigned long long u64;
typedef __attribute__((ext_vector_type(8))) short short8;     // 8 x 16-bit
typedef __attribute__((ext_vector_type(8))) unsigned short us8;
typedef __attribute__((ext_vector_type(4))) float floatx4;

union Frag2 { u64 q[2]; short8 s; };

__device__ inline u16 f2h(float f) {                // RNE fp32 -> fp16
  _Float16 h = (_Float16)f;
  return *(u16*)&h;
}

__device__ inline void async16(u16* lds, const u16* g) {
  __builtin_amdgcn_global_load_lds((const __attribute__((address_space(1))) void*)g,
                                   (__attribute__((address_space(3))) void*)lds, 16, 0, 0);
}

__device__ inline float sigf(float x) { return 1.f / (1.f + __expf(-x)); }
__device__ inline float tanh_fast(float x) { return 1.f - 2.f / (__expf(2.f * x) + 1.f); }

// Relaxed agent-scope (sc1, MALL) primitives -- the proven R8 transport.
__device__ inline u64 aload64(const u64* p) {
  return __hip_atomic_load(p, __ATOMIC_RELAXED, __HIP_MEMORY_SCOPE_AGENT);
}
__device__ inline void astore16(u16* p, u16 v) {
  __hip_atomic_store(p, v, __ATOMIC_RELAXED, __HIP_MEMORY_SCOPE_AGENT);
}
__device__ inline void astore64(u64* p, u64 v) {
  __hip_atomic_store(p, v, __ATOMIC_RELAXED, __HIP_MEMORY_SCOPE_AGENT);
}
// SWAR sentinel checks (exact; R8-proven reasoning).
__device__ inline u64 bad32(u64 v) {      // any u32 half == 0xFFFFFFFF
  u64 nv = ~v;
  return (nv - 0x0000000100000001ull) & ~nv & 0x8000000080000000ull;
}
__device__ inline u64 bad16x4(u64 v) {    // any u16 lane == 0xFFFF
  u64 nv = ~v;
  return (nv - 0x0001000100010001ull) & ~nv & 0x8000800080008000ull;
}
__device__ inline u64 packf2(float a, float b) {
  return (u64)__float_as_uint(a) | ((u64)__float_as_uint(b) << 32);
}

// LDS-only barrier: no vmcnt drain (global stores drain async; sentinel-safe).
__device__ inline void barrier_lds() {
  __builtin_amdgcn_sched_barrier(0);
  __asm__ __volatile__("s_waitcnt lgkmcnt(0)" ::: "memory");
  __builtin_amdgcn_s_barrier();
  __builtin_amdgcn_sched_barrier(0);
}

// ---------------------------------------------------------------------------
// Prep 1: W [768][640] fp32 -> WxT fp16 [640 pcol][512 k] (pcol = r*5+g),
// Wh16 fp16 [640 col][256 k] (col = g*128+r), biasp [640 pcol].
// ---------------------------------------------------------------------------
__global__ __launch_bounds__(256) void k_wprep(const float* __restrict__ W,
                                               const float* __restrict__ bias,
                                               u16* __restrict__ WxT,
                                               u16* __restrict__ Wh16,
                                               float* __restrict__ biasp) {
  int pcol = blockIdx.x;                       // 0..639
  int col  = (pcol % 5) * 128 + pcol / 5;      // original gate column
  for (int k = threadIdx.x; k < 768; k += 256) {
    float v = W[(size_t)k * 640 + col];
    if (k < 512) WxT[(size_t)pcol * 512 + k] = f2h(v);
    else         Wh16[(size_t)col * 256 + (k - 512)] = f2h(v);
  }
  if (threadIdx.x == 0) biasp[pcol] = bias[col];
}

// ---------------------------------------------------------------------------
// Prep 2: gather x [B,C,Y,X] -> xs fp16 [t][b][f].
// xs[t][b][f] = x[b][f&31][t>>3][(t&7)*16 + (f>>5)]
// ---------------------------------------------------------------------------
__global__ __launch_bounds__(256) void k_xgather(const float* __restrict__ x,
                                                 u16* __restrict__ xs) {
  int lane = threadIdx.x & 63;
  int pair = blockIdx.x * 4 + (threadIdx.x >> 6);  // t*32+b
  int t = pair >> 5, b = pair & 31;
  int y = t >> 3, x0 = (t & 7) * 16;
  int j = lane >> 2;
  int cbase = (lane & 3) * 8;
  const float* src = x + ((size_t)b * 32 * 128 + y) * 128 + x0 + j;
  us8 vh;
#pragma unroll
  for (int u = 0; u < 8; ++u)
    vh[u] = f2h(src[(size_t)(cbase + u) * 16384]);
  *(us8*)(xs + (size_t)pair * 512 + lane * 8) = vh;
}

// ---------------------------------------------------------------------------
// Input GEMM (fp16 single-plane): M=32768, N=640, K=512. 128x128 tile, BK=32.
// Gp stored [t][pcol][32 b] (16B floatx4).
// ---------------------------------------------------------------------------
__global__ __launch_bounds__(256) void k_gemm_in(const u16* __restrict__ xs,
                                                 const u16* __restrict__ WxT,
                                                 const float* __restrict__ biasp,
                                                 float* __restrict__ Gp) {
  __shared__ u16 Ah[128 * 32], Bh[128 * 32];       // 16 KB total
  const int tid = threadIdx.x;
  const int wv = tid >> 6, lane = tid & 63;
  const int quad = lane >> 4, l16 = lane & 15;
  const int m0 = blockIdx.x * 128;
  const int n0 = blockIdx.y * 128;
  const int arow = lane >> 2;
  const int acol = (lane & 3) * 8;

  floatx4 acc[4][4] = {};

  for (int kt = 0; kt < 512; kt += 32) {
#pragma unroll
    for (int i = 0; i < 2; ++i) {
      int chunk = wv * 2 + i;
      int row = chunk * 16 + arow;
      async16(&Ah[chunk * 512 + lane * 8], xs  + (size_t)(m0 + row) * 512 + kt + acol);
      async16(&Bh[chunk * 512 + lane * 8], WxT + (size_t)(n0 + row) * 512 + kt + acol);
    }
    __syncthreads();
    short8 af[4], bf[4];
#pragma unroll
    for (int mt = 0; mt < 4; ++mt)
      af[mt] = *(const short8*)&Ah[((wv & 1) * 64 + mt * 16 + l16) * 32 + quad * 8];
#pragma unroll
    for (int nt = 0; nt < 4; ++nt)
      bf[nt] = *(const short8*)&Bh[((wv >> 1) * 64 + nt * 16 + l16) * 32 + quad * 8];
#pragma unroll
    for (int mt = 0; mt < 4; ++mt)
#pragma unroll
      for (int nt = 0; nt < 4; ++nt)
        acc[mt][nt] = __builtin_amdgcn_mfma_f32_16x16x32_f16(af[mt], bf[nt], acc[mt][nt], 0, 0, 0);
    __syncthreads();
  }
#pragma unroll
  for (int nt = 0; nt < 4; ++nt) {
    int n = n0 + (wv >> 1) * 64 + nt * 16 + l16;
    float bv = biasp[n];
#pragma unroll
    for (int mt = 0; mt < 4; ++mt) {
      int mBase = m0 + (wv & 1) * 64 + mt * 16 + quad * 4;   // 4 consecutive m, same t
      int tt = mBase >> 5, bb = mBase & 31;
      floatx4 vv;
#pragma unroll
      for (int r = 0; r < 4; ++r) vv[r] = acc[mt][nt][r] + bv;
      *(floatx4*)&Gp[((size_t)tt * 640 + n) * 32 + bb] = vv;
    }
  }
}

// ---------------------------------------------------------------------------
// Persistent recurrence (R16, fp16). Grid 128: bid = h*4 + s*2 + hf.
// Block 256 thr = 4 waves = 1 wave/SIMD. ks slots: 0..3 up (k 0..127),
// 4..5 own-left, 6..7 sib. hb: fp16 h, [t*32+b][128 r] (sentinel 0xFFFF).
// cbuf: fp32 c, [t][128 r][32 b] (sentinel 0xFFFFFFFF).
// Only change vs R16: sentinel publications (hb, cbuf) issue BEFORE the
// out/LDS writes (store-queue drains consumer-visible words first).
// ---------------------------------------------------------------------------
__global__ __launch_bounds__(256, 1) void k_rec(const u16* __restrict__ Wh16,
                                                const float* __restrict__ Gp,
                                                u64* __restrict__ cbuf,
                                                u16* __restrict__ hb,
                                                float* __restrict__ out) {
  __shared__ u16 h2[2][1024];                 // [buf][16 b][64 own-r], XOR-swizzled

  const int hf = blockIdx.x & 1;
  const int s  = (blockIdx.x >> 1) & 1;
  const int h  = blockIdx.x >> 2;
  const int sb = s * 16;
  const int tid = threadIdx.x;
  const int wv = tid >> 6, lane = tid & 63;
  const int quad = lane >> 4, l16 = lane & 15;
  const int rg = hf * 64 + wv * 16 + l16;     // this lane's r
  const int b0 = sb + quad * 4;               // this lane's batch base
  const u64* hb64 = (const u64*)hb;

  // ---- Wh fp16 fragments -> registers, once. 160 regs/lane, static index.
  short8 Bw[5][8];
#pragma unroll
  for (int g = 0; g < 5; ++g) {
    const u16* p = Wh16 + (size_t)(g * 128 + rg) * 256 + quad * 8;
#pragma unroll
    for (int ks = 0; ks < 8; ++ks) {
      int kk;
      if (ks < 4)      kk = ks * 32;
      else if (ks < 6) kk = 128 + hf * 64 + (ks - 4) * 32;
      else             kk = 128 + (1 - hf) * 64 + (ks - 6) * 32;
      Bw[g][ks] = *(const short8*)(p + kk);
    }
  }

  float cl[4] = {0.f, 0.f, 0.f, 0.f};         // c_left, this lane's 4 cells

  for (int w = 0; w < 32; ++w) {
    const int t = h * 32 + w;
    const bool upok = t > 32;                 // faithful off-by-one
    const bool leftok = w > 0;

    // gate biases (plain cached loads; in flight during sweep/poll)
    floatx4 gg[5];
    {
      const float* gpb = Gp + ((size_t)t * 640 + rg * 5) * 32 + b0;
#pragma unroll
      for (int g = 0; g < 5; ++g) gg[g] = *(const floatx4*)(gpb + g * 32);
    }

    // ---- issue merged remote sweep ----
    u64 uq[4][2]; u64 sq[2][2]; u64 cq0 = 0, cq1 = 0;
    size_t ub = 0, sbase = 0, cb = 0;
    if (upok) {
      ub = (((size_t)(t - 32) * 32 + sb + l16) * 128 + quad * 8) >> 2;   // u64 idx
      cb = (((size_t)(t - 32) * 128 + rg) * 32 + b0) >> 1;
#pragma unroll
      for (int ks = 0; ks < 4; ++ks) {
        uq[ks][0] = aload64(hb64 + ub + ks * 8);
        uq[ks][1] = aload64(hb64 + ub + ks * 8 + 1);
      }
      cq0 = aload64(cbuf + cb); cq1 = aload64(cbuf + cb + 1);
    }
    if (leftok) {
      sbase = (((size_t)(t - 1) * 32 + sb + l16) * 128 + (1 - hf) * 64 + quad * 8) >> 2;
#pragma unroll
      for (int j = 0; j < 2; ++j) {
        sq[j][0] = aload64(hb64 + sbase + j * 8);
        sq[j][1] = aload64(hb64 + sbase + j * 8 + 1);
      }
    }

    floatx4 acc[5] = {};

    // ---- phase A: own-left MFMAs from LDS (hide the remote RT) ----
    if (leftok) {
      const int bsel = (w - 1) & 1;
#pragma unroll
      for (int j = 0; j < 2; ++j) {
        int idx = (l16 * 64 + j * 32 + quad * 8) ^ ((l16 & 7) << 3);
        short8 a = *(const short8*)&h2[bsel][idx];
#pragma unroll
        for (int g = 0; g < 5; ++g)
          acc[g] = __builtin_amdgcn_mfma_f32_16x16x32_f16(a, Bw[g][4 + j], acc[g], 0, 0, 0);
      }
    }

    // ---- poll: one detect for all remote deps ----
    if (upok | (int)leftok) {
      for (;;) {
        u64 bad = 0;
        if (upok) {
#pragma unroll
          for (int ks = 0; ks < 4; ++ks) bad |= bad16x4(uq[ks][0]) | bad16x4(uq[ks][1]);
          bad |= bad32(cq0) | bad32(cq1);
        }
        if (leftok) {
#pragma unroll
          for (int j = 0; j < 2; ++j) bad |= bad16x4(sq[j][0]) | bad16x4(sq[j][1]);
        }
        if (!bad) break;
        __builtin_amdgcn_s_sleep(1);
        __asm__ __volatile__("" ::: "memory");
        if (upok) {
#pragma unroll
          for (int ks = 0; ks < 4; ++ks) {
            uq[ks][0] = aload64(hb64 + ub + ks * 8);
            uq[ks][1] = aload64(hb64 + ub + ks * 8 + 1);
          }
          cq0 = aload64(cbuf + cb); cq1 = aload64(cbuf + cb + 1);
        }
        if (leftok) {
#pragma unroll
          for (int j = 0; j < 2; ++j) {
            sq[j][0] = aload64(hb64 + sbase + j * 8);
            sq[j][1] = aload64(hb64 + sbase + j * 8 + 1);
          }
        }
      }
    }

    // ---- phase B: remote-dep MFMAs ----
    if (upok) {
#pragma unroll
      for (int ks = 0; ks < 4; ++ks) {
        Frag2 f; f.q[0] = uq[ks][0]; f.q[1] = uq[ks][1];
#pragma unroll
        for (int g = 0; g < 5; ++g)
          acc[g] = __builtin_amdgcn_mfma_f32_16x16x32_f16(f.s, Bw[g][ks], acc[g], 0, 0, 0);
      }
    }
    if (leftok) {
#pragma unroll
      for (int j = 0; j < 2; ++j) {
        Frag2 f; f.q[0] = sq[j][0]; f.q[1] = sq[j][1];
#pragma unroll
        for (int g = 0; g < 5; ++g)
          acc[g] = __builtin_amdgcn_mfma_f32_16x16x32_f16(f.s, Bw[g][6 + j], acc[g], 0, 0, 0);
      }
    }

    // ---- in-register epilogue: lane's 4 cells (b0+u, rg) ----
    float c1v[4];
    c1v[0] = __uint_as_float((u32)cq0); c1v[1] = __uint_as_float((u32)(cq0 >> 32));
    c1v[2] = __uint_as_float((u32)cq1); c1v[3] = __uint_as_float((u32)(cq1 >> 32));
    const int cur = w & 1;
    float nh4[4]; u16 hv4[4];
#pragma unroll
    for (int u = 0; u < 4; ++u) {
      float gi = acc[0][u] + gg[0][u];
      float gj = acc[1][u] + gg[1][u];
      float ga = acc[2][u] + gg[2][u];
      float gb = acc[3][u] + gg[3][u];
      float go = acc[4][u] + gg[4][u];
      float c1 = upok ? c1v[u] : 0.f;
      float c2 = leftok ? cl[u] : 0.f;
      float nc = c1 * sigf(ga) + c2 * sigf(gb) + sigf(gi) * tanh_fast(gj);
      float nh = tanh_fast(nc) * sigf(go);
      cl[u] = nc;
      nh4[u] = nh;
      u16 hv = f2h(nh);
      hv4[u] = hv;
      astore16(hb + ((size_t)t * 32 + b0 + u) * 128 + rg, hv);       // sentinel publish
    }
    size_t cw = (((size_t)t * 128 + rg) * 32 + b0) >> 1;
    astore64(cbuf + cw,     packf2(cl[0], cl[1]));                   // sentinel publish
    astore64(cbuf + cw + 1, packf2(cl[2], cl[3]));
    // non-consumed writes AFTER all sentinel publications (store-queue order)
#pragma unroll
    for (int u = 0; u < 4; ++u) {
      out[(((size_t)(b0 + u) * 32 + h) * 32 + w) * 128 + rg] = nh4[u];
      int bl = quad * 4 + u;
      h2[cur][(bl * 64 + wv * 16 + l16) ^ ((bl & 7) << 3)] = hv4[u];
    }

    barrier_lds();   // LDS-only: no vmcnt drain on the critical path
  }
}

// ---------------------------------------------------------------------------
extern "C" void kernel_launch(void* const* d_in, const int* in_sizes, int n_in,
                              void* d_out, int out_size, void* d_ws, size_t ws_size,
                              hipStream_t stream) {
  const float* x    = (const float*)d_in[0];   // [32,32,128,128]
  const float* W    = (const float*)d_in[1];   // [768,640]
  const float* bias = (const float*)d_in[2];   // [640]
  float* out = (float*)d_out;                  // [32,32,32,128]
  char* ws = (char*)d_ws;

  size_t off = 0;
  u16*   xs    = (u16*)(ws + off);  off += (size_t)32768 * 512 * 2;  // 33.6 MB
  u16*   WxT   = (u16*)(ws + off);  off += (size_t)640 * 512 * 2;    // 0.65 MB
  u16*   Wh16  = (u16*)(ws + off);  off += (size_t)640 * 256 * 2;    // 0.33 MB
  float* biasp = (float*)(ws + off); off += (size_t)640 * 4;
  float* Gp    = (float*)(ws + off); off += (size_t)1024 * 640 * 32 * 4; // 83.9 MB
  // sentinel-initialized state (contiguous 25.2 MB memset 0xFF)
  u64*   cbuf  = (u64*)(ws + off);  off += (size_t)1024 * 128 * 32 * 4;  // 16.8 MB
  u16*   hb    = (u16*)(ws + off);  off += (size_t)32768 * 128 * 2;      // 8.4 MB
  (void)ws_size;

  hipMemsetAsync(cbuf, 0xFF, (size_t)1024 * 128 * 32 * 4 + (size_t)32768 * 128 * 2, stream);
  k_wprep<<<dim3(640), dim3(256), 0, stream>>>(W, bias, WxT, Wh16, biasp);
  k_xgather<<<dim3(8192), dim3(256), 0, stream>>>(x, xs);
  k_gemm_in<<<dim3(256, 5), dim3(256), 0, stream>>>(xs, WxT, biasp, Gp);
  k_rec<<<dim3(128), dim3(256), 0, stream>>>(Wh16, Gp, cbuf, hb, out);
}